// Round 12
// baseline (3629.504 us; speedup 1.0000x reference)
//
#include <hip/hip_runtime.h>
#include <stdint.h>

typedef unsigned int u32;
typedef unsigned short u16;
typedef __attribute__((ext_vector_type(8))) short bf16x8;   // 8 bf16 = 4 VGPRs
typedef __attribute__((ext_vector_type(4))) float f32x4;

#define DEV __device__ __forceinline__
#define BN_EPS 1e-5f

DEV u16 f2bf(float f){ u32 x = __float_as_uint(f); return (u16)((x + 0x7FFFu + ((x >> 16) & 1u)) >> 16); }

// ---------------------------------------------------------------- DPP wave64 argmax/argmin reduce
template<int CTRL, int RMASK, bool MAXOP>
DEV void dpp_step(float& d, u32& i){
  int ds = __float_as_int(d);
  int is = (int)i;
  int dn_ = __builtin_amdgcn_update_dpp(ds, ds, CTRL, RMASK, 0xf, false);
  int in_ = __builtin_amdgcn_update_dpp(is, is, CTRL, RMASK, 0xf, false);
  float dn = __int_as_float(dn_);
  u32 ii = (u32)in_;
  bool take = MAXOP ? (dn > d || (dn == d && ii < i))
                    : (dn < d || (dn == d && ii < i));
  if (take){ d = dn; i = ii; }
}

template<bool MAXOP>
DEV u32 dpp_arg_reduce(float& d, u32& i){
  dpp_step<0x111, 0xf, MAXOP>(d, i);  // row_shr:1
  dpp_step<0x112, 0xf, MAXOP>(d, i);  // row_shr:2
  dpp_step<0x114, 0xf, MAXOP>(d, i);  // row_shr:4
  dpp_step<0x118, 0xf, MAXOP>(d, i);  // row_shr:8
  dpp_step<0x142, 0xa, MAXOP>(d, i);  // row_bcast15 -> rows 1,3
  dpp_step<0x143, 0xc, MAXOP>(d, i);  // row_bcast31 -> rows 2,3
  return (u32)__builtin_amdgcn_readlane((int)i, 63);
}

// log2-depth register mux: returns a[slot], slot in [0,N)
template<int N>
DEV float muxN(const float* a, int slot){
  if constexpr (N == 1){
    return a[0];
  } else {
    float m[N / 2];
#pragma unroll
    for (int i = 0; i < N / 2; ++i) m[i] = (slot & 1) ? a[2 * i + 1] : a[2 * i];
    return muxN<N / 2>(m, slot >> 1);
  }
}

// ---------------------------------------------------------------- ws-too-small fallback
__global__ void kfb(float* out, int n, float code){
  int i = blockIdx.x * 256 + threadIdx.x;
  if (i < n) out[i] = (i == 0) ? code : 0.f;
}

// cast weights to bf16
__global__ void kcast_bf(const float* __restrict__ src, int rows, int cols, int srcStride, int colOff,
                         u16* __restrict__ dst){
  int i = blockIdx.x * 256 + threadIdx.x;
  if (i >= rows * cols) return;
  int r = i / cols, c = i - r * cols;
  dst[r * cols + c] = f2bf(src[r * srcStride + colOff + c]);
}

// ---------------------------------------------------------------- stage A: BN1 stats (deterministic)
__global__ __launch_bounds__(256) void kA_stats(const float* __restrict__ x, const float* __restrict__ w,
                                                const float* __restrict__ g, const float* __restrict__ b,
                                                float* __restrict__ sc, float* __restrict__ sh){
  int c = blockIdx.x, t = threadIdx.x;
  float wr[6];
#pragma unroll
  for (int j = 0; j < 6; ++j) wr[j] = w[c * 6 + j];
  float s = 0.f, ss = 0.f;
  for (int i = t; i < 32768; i += 256){
    int bb = i >> 10, n = i & 1023;
    const float* xb = x + bb * 6144 + n;
    float y = 0.f;
#pragma unroll
    for (int j = 0; j < 6; ++j) y += wr[j] * xb[j * 1024];
    s += y; ss += y * y;
  }
  __shared__ float rs[256], rq[256];
  rs[t] = s; rq[t] = ss; __syncthreads();
  for (int k = 128; k >= 1; k >>= 1){
    if (t < k){ rs[t] += rs[t + k]; rq[t] += rq[t + k]; }
    __syncthreads();
  }
  if (t == 0){
    float m = rs[0] * (1.f / 32768.f), e2 = rq[0] * (1.f / 32768.f);
    float var = e2 - m * m; if (var < 0.f) var = 0.f;
    float scv = g[c] * rsqrtf(var + BN_EPS);
    sc[c] = scv; sh[c] = b[c] - m * scv;
  }
}

// stage A apply -> featT f32 [b][n][64]
__global__ __launch_bounds__(256) void kA_feat(const float* __restrict__ x, const float* __restrict__ w,
                                               const float* __restrict__ sc, const float* __restrict__ sh,
                                               float* __restrict__ featT){
  int b = blockIdx.x >> 2, t = threadIdx.x;
  int n = ((blockIdx.x & 3) << 8) + t;
  __shared__ float wl[384], scl[64], shl[64];
  for (int u = t; u < 384; u += 256) wl[u] = w[u];
  if (t < 64){ scl[t] = sc[t]; shl[t] = sh[t]; }
  __syncthreads();
  float v[6];
  const float* xb = x + b * 6144 + n;
#pragma unroll
  for (int j = 0; j < 6; ++j) v[j] = xb[j * 1024];
  float* row = featT + ((size_t)b * 1024 + n) * 64;
#pragma unroll
  for (int c = 0; c < 64; ++c){
    float y = 0.f;
#pragma unroll
    for (int j = 0; j < 6; ++j) y += wl[c * 6 + j] * v[j];
    y = scl[c] * y + shl[c];
    row[c] = fmaxf(y, 0.f);
  }
}

// ---------------------------------------------------------------- x_skip pre-act f32 [b][1024][256]
__global__ __launch_bounds__(256) void kxskip_pre(const float* __restrict__ featT, const float* __restrict__ w2,
                                                  float* __restrict__ xpre){
  int b = blockIdx.x >> 8, m = blockIdx.x & 255, t = threadIdx.x;
  __shared__ float row[64];
  if (t < 64) row[t] = featT[((size_t)b * 1024 + 4 * m) * 64 + t];
  __syncthreads();
#pragma unroll
  for (int rep = 0; rep < 4; ++rep){
    int o = rep * 256 + t;
    float acc = 0.f;
    const float* wr = w2 + (size_t)o * 64;
#pragma unroll
    for (int c = 0; c < 64; ++c) acc += wr[c] * row[c];
    xpre[((size_t)b * 1024 + o) * 256 + m] = acc;
  }
}

__global__ __launch_bounds__(256) void kxskip_stats(const float* __restrict__ xpre, const float* __restrict__ g,
                                                    const float* __restrict__ b, float* __restrict__ sc,
                                                    float* __restrict__ sh){
  int o = blockIdx.x, t = threadIdx.x;
  float s = 0.f, ss = 0.f;
  for (int i = t; i < 8192; i += 256){
    int bb = i >> 8, m = i & 255;
    float v = xpre[((size_t)bb * 1024 + o) * 256 + m];
    s += v; ss += v * v;
  }
  __shared__ float rs[256], rq[256];
  rs[t] = s; rq[t] = ss; __syncthreads();
  for (int k = 128; k >= 1; k >>= 1){
    if (t < k){ rs[t] += rs[t + k]; rq[t] += rq[t + k]; }
    __syncthreads();
  }
  if (t == 0){
    float m = rs[0] * (1.f / 8192.f), e2 = rq[0] * (1.f / 8192.f);
    float var = e2 - m * m; if (var < 0.f) var = 0.f;
    float scv = g[o] * rsqrtf(var + BN_EPS);
    sc[o] = scv; sh[o] = b[o] - m * scv;
  }
}

// ---------------------------------------------------------------- FPS: DPP argmax, f32 np-order
// __launch_bounds__(64, 1): grid is only 32 blocks; allow full VGPR budget so
// px/py/pz/dd[PPL] stay in registers (R10/R11 spilled at default budget: VGPR=52/56 < 64 needed)
template<int NPTS, int NSAMP, int PSTRIDE>
__global__ __launch_bounds__(64, 1) void kfps(const float* __restrict__ px_, const float* __restrict__ py_,
                                              const float* __restrict__ pz_, int bstride,
                                              int* __restrict__ fidx, float* __restrict__ nxyz){
  constexpr int PPL = NPTS / 64;
  int b = blockIdx.x, lane = threadIdx.x;
  const float* pxb = px_ + (size_t)b * bstride;
  const float* pyb = py_ + (size_t)b * bstride;
  const float* pzb = pz_ + (size_t)b * bstride;
  float px[PPL], py[PPL], pz[PPL], dd[PPL];
#pragma unroll
  for (int j = 0; j < PPL; ++j){
    int p = j * 64 + lane;
    px[j] = pxb[p * PSTRIDE]; py[j] = pyb[p * PSTRIDE]; pz[j] = pzb[p * PSTRIDE];
    dd[j] = 1e10f;
  }
  float cx = __int_as_float(__builtin_amdgcn_readlane(__float_as_int(px[0]), 0));
  float cy = __int_as_float(__builtin_amdgcn_readlane(__float_as_int(py[0]), 0));
  float cz = __int_as_float(__builtin_amdgcn_readlane(__float_as_int(pz[0]), 0));
  if (lane == 0){
    fidx[(size_t)b * NSAMP] = 0;
    nxyz[(size_t)b * NSAMP * 3 + 0] = cx;
    nxyz[(size_t)b * NSAMP * 3 + 1] = cy;
    nxyz[(size_t)b * NSAMP * 3 + 2] = cz;
  }
  for (int s = 1; s < NSAMP; ++s){
    float nd[PPL]; u32 ni[PPL];
#pragma unroll
    for (int j = 0; j < PPL; ++j){
      float dx = __fsub_rn(px[j], cx);
      float dy = __fsub_rn(py[j], cy);
      float dz = __fsub_rn(pz[j], cz);
      float d = __fadd_rn(__fadd_rn(__fmul_rn(dx, dx), __fmul_rn(dy, dy)), __fmul_rn(dz, dz));
      float v = fminf(dd[j], d);
      dd[j] = v;
      nd[j] = v; ni[j] = (u32)(j * 64 + lane);
    }
    // per-lane ILP tree (ni increasing in j -> lower j wins ties, matching serial scan)
#pragma unroll
    for (int w = PPL / 2; w >= 1; w >>= 1){
#pragma unroll
      for (int j = 0; j < PPL; ++j){
        if (j < w){
          if (nd[j + w] > nd[j] || (nd[j + w] == nd[j] && ni[j + w] < ni[j])){
            nd[j] = nd[j + w]; ni[j] = ni[j + w];
          }
        }
      }
    }
    float bd = nd[0]; u32 bi = ni[0];
    u32 win = dpp_arg_reduce<true>(bd, bi);
    int slot = (int)(win >> 6), wl = (int)(win & 63u);
    float sx = muxN<PPL>(px, slot);
    float sy = muxN<PPL>(py, slot);
    float sz = muxN<PPL>(pz, slot);
    cx = __int_as_float(__builtin_amdgcn_readlane(__float_as_int(sx), wl));
    cy = __int_as_float(__builtin_amdgcn_readlane(__float_as_int(sy), wl));
    cz = __int_as_float(__builtin_amdgcn_readlane(__float_as_int(sz), wl));
    if (lane == 0){
      fidx[(size_t)b * NSAMP + s] = (int)win;
      nxyz[((size_t)b * NSAMP + s) * 3 + 0] = cx;
      nxyz[((size_t)b * NSAMP + s) * 3 + 1] = cy;
      nxyz[((size_t)b * NSAMP + s) * 3 + 2] = cz;
    }
  }
}

// ---------------------------------------------------------------- kNN: DPP argmin, 4 waves/block
// (256, 2): budget 256 VGPRs so kd/kp + reduce temps stay in registers
template<int NPTS, int SOUT>
__global__ __launch_bounds__(256, 2) void kknn(const float* __restrict__ px_, const float* __restrict__ py_,
                                               const float* __restrict__ pz_, int bstride, int pstride,
                                               const float* __restrict__ cxyz, int* __restrict__ knn){
  constexpr int PPL = NPTS / 64;
  int wid = blockIdx.x * 4 + (threadIdx.x >> 6);
  int lane = threadIdx.x & 63;
  int b = wid / SOUT, s = wid - b * SOUT;
  const float* cb = cxyz + ((size_t)b * SOUT + s) * 3;
  float cx = cb[0], cy = cb[1], cz = cb[2];
  float csq = __fadd_rn(__fadd_rn(__fmul_rn(cx, cx), __fmul_rn(cy, cy)), __fmul_rn(cz, cz));
  float kd[PPL]; u32 kp[PPL];
#pragma unroll
  for (int j = 0; j < PPL; ++j){
    int p = j * 64 + lane;
    float xx = px_[(size_t)b * bstride + p * pstride];
    float yy = py_[(size_t)b * bstride + p * pstride];
    float zz = pz_[(size_t)b * bstride + p * pstride];
    float psq = __fadd_rn(__fadd_rn(__fmul_rn(xx, xx), __fmul_rn(yy, yy)), __fmul_rn(zz, zz));
    float dot = __fadd_rn(__fadd_rn(__fmul_rn(cx, xx), __fmul_rn(cy, yy)), __fmul_rn(cz, zz));
    kd[j] = __fsub_rn(__fadd_rn(csq, psq), __fmul_rn(2.f, dot));
    kp[j] = (u32)p;
  }
  int* outp = knn + ((size_t)b * SOUT + s) * 32;
  for (int k = 0; k < 32; ++k){
    float nd[PPL]; u32 ni[PPL];
#pragma unroll
    for (int j = 0; j < PPL; ++j){ nd[j] = kd[j]; ni[j] = kp[j]; }
#pragma unroll
    for (int w = PPL / 2; w >= 1; w >>= 1){
#pragma unroll
      for (int j = 0; j < PPL; ++j){
        if (j < w){
          if (nd[j + w] < nd[j] || (nd[j + w] == nd[j] && ni[j + w] < ni[j])){
            nd[j] = nd[j + w]; ni[j] = ni[j + w];
          }
        }
      }
    }
    float bd = nd[0]; u32 bi = ni[0];
    u32 win = dpp_arg_reduce<false>(bd, bi);
    if (lane == 0) outp[k] = (int)win;
#pragma unroll
    for (int j = 0; j < PPL; ++j) if (kp[j] == win) kd[j] = 3e38f;
  }
}

// ---------------------------------------------------------------- local_op via MFMA (unchanged)
template<int CIN, int C, int NPTSRC, int SLOG, int FULL>
__global__ __launch_bounds__(256) void kgm(const float* __restrict__ featSrc, const int* __restrict__ knnIdx,
                                           const int* __restrict__ fidx, const float* __restrict__ w1f,
                                           const u16* __restrict__ w1bf,
                                           const float* __restrict__ sc1g, const float* __restrict__ sh1g,
                                           const u16* __restrict__ w2bf, const float* __restrict__ gp,
                                           float* __restrict__ part, float* __restrict__ pooledPre){
  constexpr int MT  = C / 64;
  constexpr int KS1 = CIN / 32;
  constexpr int KS2 = C / 32;
  constexpr int P1  = CIN + 8;
  constexpr int P2  = C + 8;
  int g = blockIdx.x, t = threadIdx.x, b = g >> SLOG;
  int l = t & 63, wv = t >> 6;
  int lg = l >> 4, ln = l & 15;

  __shared__ int   idxs[32];
  __shared__ float cen[CIN];
  __shared__ float bias[C];
  __shared__ float sc1s[FULL ? C : 1], sh1s[FULL ? C : 1];
  __shared__ u16   gsT[32][P1];
  __shared__ u16   act2[FULL ? 32 : 1][FULL ? P2 : 1];

  if (t < 32) idxs[t] = knnIdx[(size_t)g * 32 + t];
  for (int u = t; u < CIN; u += 256) cen[u] = featSrc[((size_t)(b * NPTSRC + fidx[g])) * CIN + u];
  if (FULL && t < C){ sc1s[t] = sc1g[t]; sh1s[t] = sh1g[t]; }
  __syncthreads();

  for (int u = t; u < 32 * CIN / 4; u += 256){
    int k = u & 31, c4 = u >> 5;
    float4 v = *(const float4*)(featSrc + ((size_t)(b * NPTSRC + idxs[k])) * CIN + c4 * 4);
    u16 b0 = f2bf(v.x - cen[c4 * 4 + 0]), b1 = f2bf(v.y - cen[c4 * 4 + 1]);
    u16 b2 = f2bf(v.z - cen[c4 * 4 + 2]), b3 = f2bf(v.w - cen[c4 * 4 + 3]);
    *(uint2*)&gsT[k][c4 * 4] = make_uint2((u32)b0 | ((u32)b1 << 16), (u32)b2 | ((u32)b3 << 16));
  }
  if (t < C){
    const float* wr = w1f + (size_t)t * (2 * CIN) + CIN;
    float bs = 0.f;
#pragma unroll 4
    for (int c = 0; c < CIN; ++c) bs += wr[c] * cen[c];
    bias[t] = bs;
  }
  __syncthreads();

  f32x4 acc[MT][2];
#pragma unroll
  for (int mt = 0; mt < MT; ++mt){ acc[mt][0] = (f32x4)0.f; acc[mt][1] = (f32x4)0.f; }
#pragma unroll
  for (int ks = 0; ks < KS1; ++ks){
    int c0 = ks * 32 + lg * 8;
    bf16x8 bfr0 = *(const bf16x8*)&gsT[ln][c0];
    bf16x8 bfr1 = *(const bf16x8*)&gsT[16 + ln][c0];
#pragma unroll
    for (int mt = 0; mt < MT; ++mt){
      int o0 = wv * (C / 4) + mt * 16;
      bf16x8 afr = *(const bf16x8*)(w1bf + (size_t)(o0 + ln) * CIN + c0);
      acc[mt][0] = __builtin_amdgcn_mfma_f32_16x16x32_bf16(afr, bfr0, acc[mt][0], 0, 0, 0);
      acc[mt][1] = __builtin_amdgcn_mfma_f32_16x16x32_bf16(afr, bfr1, acc[mt][1], 0, 0, 0);
    }
  }

  if (!FULL){
#pragma unroll
    for (int mt = 0; mt < MT; ++mt){
      int obase = wv * (C / 4) + mt * 16 + lg * 4;
#pragma unroll
      for (int j = 0; j < 4; ++j){
        float bv = bias[obase + j];
        float vA = acc[mt][0][j] + bv, vB = acc[mt][1][j] + bv;
        float s = vA + vB, ss = vA * vA + vB * vB;
#pragma unroll
        for (int mk = 1; mk < 16; mk <<= 1){ s += __shfl_xor(s, mk, 64); ss += __shfl_xor(ss, mk, 64); }
        if (ln == 0){
          part[((size_t)g * C + obase + j) * 2 + 0] = s;
          part[((size_t)g * C + obase + j) * 2 + 1] = ss;
        }
      }
    }
    return;
  }

#pragma unroll
  for (int mt = 0; mt < MT; ++mt){
    int obase = wv * (C / 4) + mt * 16 + lg * 4;
#pragma unroll
    for (int nt = 0; nt < 2; ++nt){
      u16 h[4];
#pragma unroll
      for (int j = 0; j < 4; ++j){
        int o = obase + j;
        float v = fmaxf(sc1s[o] * (acc[mt][nt][j] + bias[o]) + sh1s[o], 0.f);
        h[j] = f2bf(v);
      }
      *(uint2*)&act2[nt * 16 + ln][obase] =
          make_uint2((u32)h[0] | ((u32)h[1] << 16), (u32)h[2] | ((u32)h[3] << 16));
    }
  }
  __syncthreads();

#pragma unroll
  for (int mt = 0; mt < MT; ++mt){ acc[mt][0] = (f32x4)0.f; acc[mt][1] = (f32x4)0.f; }
#pragma unroll
  for (int ks = 0; ks < KS2; ++ks){
    int c0 = ks * 32 + lg * 8;
    bf16x8 bfr0 = *(const bf16x8*)&act2[ln][c0];
    bf16x8 bfr1 = *(const bf16x8*)&act2[16 + ln][c0];
#pragma unroll
    for (int mt = 0; mt < MT; ++mt){
      int o0 = wv * (C / 4) + mt * 16;
      bf16x8 afr = *(const bf16x8*)(w2bf + (size_t)(o0 + ln) * C + c0);
      acc[mt][0] = __builtin_amdgcn_mfma_f32_16x16x32_bf16(afr, bfr0, acc[mt][0], 0, 0, 0);
      acc[mt][1] = __builtin_amdgcn_mfma_f32_16x16x32_bf16(afr, bfr1, acc[mt][1], 0, 0, 0);
    }
  }

#pragma unroll
  for (int mt = 0; mt < MT; ++mt){
    int obase = wv * (C / 4) + mt * 16 + lg * 4;
#pragma unroll
    for (int j = 0; j < 4; ++j){
      float vA = acc[mt][0][j], vB = acc[mt][1][j];
      float s = vA + vB, ss = vA * vA + vB * vB;
      float mx = fmaxf(vA, vB), mn = fminf(vA, vB);
#pragma unroll
      for (int mk = 1; mk < 16; mk <<= 1){
        s += __shfl_xor(s, mk, 64); ss += __shfl_xor(ss, mk, 64);
        mx = fmaxf(mx, __shfl_xor(mx, mk, 64)); mn = fminf(mn, __shfl_xor(mn, mk, 64));
      }
      if (ln == 0){
        int o = obase + j;
        part[((size_t)g * C + o) * 2 + 0] = s;
        part[((size_t)g * C + o) * 2 + 1] = ss;
        pooledPre[(size_t)g * C + o] = (gp[o] >= 0.f) ? mx : mn;
      }
    }
  }
}

// reduce per-group partials -> BN scale/shift (deterministic)
template<int C, int NG>
__global__ __launch_bounds__(256) void kstats_part(const float* __restrict__ part, const float* __restrict__ g_,
                                                   const float* __restrict__ b_, float* __restrict__ sc,
                                                   float* __restrict__ sh){
  int o = blockIdx.x, t = threadIdx.x;
  float s = 0.f, ss = 0.f;
  for (int i = t; i < NG; i += 256){
    s  += part[((size_t)i * C + o) * 2 + 0];
    ss += part[((size_t)i * C + o) * 2 + 1];
  }
  __shared__ float rs[256], rq[256];
  rs[t] = s; rq[t] = ss; __syncthreads();
  for (int k = 128; k >= 1; k >>= 1){
    if (t < k){ rs[t] += rs[t + k]; rq[t] += rq[t + k]; }
    __syncthreads();
  }
  if (t == 0){
    const float inv_n = 1.f / (float)(NG * 32);
    float m = rs[0] * inv_n, e2 = rq[0] * inv_n;
    float var = e2 - m * m; if (var < 0.f) var = 0.f;
    float scv = g_[o] * rsqrtf(var + BN_EPS);
    sc[o] = scv; sh[o] = b_[o] - m * scv;
  }
}

// finalize pooled (stage1): f0feat f32 [b*512+s][128]
__global__ void kpool_fin1(const float* __restrict__ pooledPre, const float* __restrict__ sc,
                           const float* __restrict__ sh, float* __restrict__ f0feat){
  int i = blockIdx.x * 256 + threadIdx.x;
  if (i >= 16384 * 128) return;
  int o = i & 127;
  float v = sc[o] * pooledPre[i] + sh[o];
  f0feat[i] = fmaxf(v, 0.f);
}

// finalize pooled (stage2): f1T f32 [b][c][s]
__global__ void kpool_finT(const float* __restrict__ pooledPre, const float* __restrict__ sc,
                           const float* __restrict__ sh, float* __restrict__ f1T){
  int i = blockIdx.x * 256 + threadIdx.x;
  if (i >= 8192 * 256) return;
  int gg = i >> 8, o = i & 255;
  int b = gg >> 8, s = gg & 255;
  float v = sc[o] * pooledPre[i] + sh[o];
  f1T[((size_t)(b * 256 + o)) * 256 + s] = fmaxf(v, 0.f);
}

// ---------------------------------------------------------------- final GEMM: block = (b, 8-o tile), thread = m
__global__ __launch_bounds__(256) void kfinal8(const float* __restrict__ f1T, const float* __restrict__ xpre,
                                               const float* __restrict__ scS, const float* __restrict__ shS,
                                               const float* __restrict__ wf, float* __restrict__ finpre){
  int b = blockIdx.x >> 6, ot = blockIdx.x & 63, m = threadIdx.x;
  int o0 = ot * 8;
  const float* wb = wf + (size_t)o0 * 1280;
  float acc[8];
#pragma unroll
  for (int j = 0; j < 8; ++j) acc[j] = 0.f;
  const float* fb = f1T + (size_t)b * 256 * 256 + m;
  for (int k = 0; k < 256; ++k){
    float v = fb[(size_t)k * 256];
#pragma unroll
    for (int j = 0; j < 8; ++j) acc[j] = fmaf(wb[(size_t)j * 1280 + k], v, acc[j]);
  }
  const float* xb = xpre + (size_t)b * 1024 * 256 + m;
  for (int k = 0; k < 1024; ++k){
    float xv = xb[(size_t)k * 256];
    float v = fmaxf(scS[k] * xv + shS[k], 0.f);
#pragma unroll
    for (int j = 0; j < 8; ++j) acc[j] = fmaf(wb[(size_t)j * 1280 + 256 + k], v, acc[j]);
  }
#pragma unroll
  for (int j = 0; j < 8; ++j)
    finpre[((size_t)b * 512 + o0 + j) * 256 + m] = acc[j];
}

__global__ __launch_bounds__(256) void kstats_fin(const float* __restrict__ finpre, const float* __restrict__ g,
                                                  const float* __restrict__ b, float* __restrict__ sc,
                                                  float* __restrict__ sh){
  int o = blockIdx.x, t = threadIdx.x;
  float s = 0.f, ss = 0.f;
  for (int i = t; i < 8192; i += 256){
    int bb = i >> 8, m = i & 255;
    float v = finpre[((size_t)bb * 512 + o) * 256 + m];
    s += v; ss += v * v;
  }
  __shared__ float rs[256], rq[256];
  rs[t] = s; rq[t] = ss; __syncthreads();
  for (int k = 128; k >= 1; k >>= 1){
    if (t < k){ rs[t] += rs[t + k]; rq[t] += rq[t + k]; }
    __syncthreads();
  }
  if (t == 0){
    float m = rs[0] * (1.f / 8192.f), e2 = rq[0] * (1.f / 8192.f);
    float var = e2 - m * m; if (var < 0.f) var = 0.f;
    float scv = g[o] * rsqrtf(var + BN_EPS);
    sc[o] = scv; sh[o] = b[o] - m * scv;
  }
}

__global__ void kapply(const float* __restrict__ finpre, const float* __restrict__ sc,
                       const float* __restrict__ sh, float* __restrict__ out){
  int i = blockIdx.x * 256 + threadIdx.x;
  if (i >= 32 * 512 * 256) return;
  int o = (i >> 8) & 511;
  float v = sc[o] * finpre[i] + sh[o];
  out[i] = v > 0.f ? v : 0.2f * v;
}

// ================================================================ host
extern "C" void kernel_launch(void* const* d_in, const int* in_sizes, int n_in,
                              void* d_out, int out_size, void* d_ws, size_t ws_size,
                              hipStream_t stream){
  const float* x    = (const float*)d_in[0];
  const float* w_c1 = (const float*)d_in[1];
  const float* g1   = (const float*)d_in[2];
  const float* b1   = (const float*)d_in[3];
  const float* w_c2 = (const float*)d_in[4];
  const float* g2   = (const float*)d_in[5];
  const float* b2   = (const float*)d_in[6];
  const float* l0w1 = (const float*)d_in[7];
  const float* l0g1 = (const float*)d_in[8];
  const float* l0b1 = (const float*)d_in[9];
  const float* l0w2 = (const float*)d_in[10];
  const float* l0g2 = (const float*)d_in[11];
  const float* l0b2 = (const float*)d_in[12];
  const float* l1w1 = (const float*)d_in[13];
  const float* l1g1 = (const float*)d_in[14];
  const float* l1b1 = (const float*)d_in[15];
  const float* l1w2 = (const float*)d_in[16];
  const float* l1g2 = (const float*)d_in[17];
  const float* l1b2 = (const float*)d_in[18];
  const float* wf   = (const float*)d_in[19];
  const float* gf   = (const float*)d_in[20];
  const float* bfp  = (const float*)d_in[21];
  float* out = (float*)d_out;

  char* ws = (char*)d_ws;
  size_t cur = 0;
  auto alloc = [&](size_t bytes) -> char* {
    char* p = ws + cur;
    cur += (bytes + 255) & ~(size_t)255;
    return p;
  };
  float* sc1  = (float*)alloc(64 * 4);    float* sh1  = (float*)alloc(64 * 4);
  float* scSK = (float*)alloc(1024 * 4);  float* shSK = (float*)alloc(1024 * 4);
  float* scA1 = (float*)alloc(128 * 4);   float* shA1 = (float*)alloc(128 * 4);
  float* scA2 = (float*)alloc(128 * 4);   float* shA2 = (float*)alloc(128 * 4);
  float* scC1 = (float*)alloc(256 * 4);   float* shC1 = (float*)alloc(256 * 4);
  float* scC2 = (float*)alloc(256 * 4);   float* shC2 = (float*)alloc(256 * 4);
  float* scF  = (float*)alloc(512 * 4);   float* shF  = (float*)alloc(512 * 4);
  u16* w1bf1 = (u16*)alloc((size_t)128 * 64 * 2);
  u16* w2bf1 = (u16*)alloc((size_t)128 * 128 * 2);
  u16* w1bf2 = (u16*)alloc((size_t)256 * 128 * 2);
  u16* w2bf2 = (u16*)alloc((size_t)256 * 256 * 2);
  float* featT  = (float*)alloc((size_t)32 * 1024 * 64 * 4);
  float* xpre   = (float*)alloc((size_t)32 * 1024 * 256 * 4);
  int*   fidx1  = (int*)  alloc((size_t)32 * 512 * 4);
  float* nxyz1  = (float*)alloc((size_t)32 * 512 * 3 * 4);
  int*   knn1   = (int*)  alloc((size_t)32 * 512 * 32 * 4);
  int*   fidx2  = (int*)  alloc((size_t)32 * 256 * 4);
  float* nxyz2  = (float*)alloc((size_t)32 * 256 * 3 * 4);
  int*   knn2   = (int*)  alloc((size_t)32 * 256 * 32 * 4);
  float* part   = (float*)alloc((size_t)16384 * 128 * 2 * 4);  // == 8192*256*2, reused by stage 2
  float* pooledPre = (float*)alloc((size_t)16384 * 128 * 4);   // == 8192*256, reused by stage 2
  float* f0feat = (float*)alloc((size_t)16384 * 128 * 4);
  float* f1T    = (float*)alloc((size_t)32 * 256 * 256 * 4);
  float* finpre = (float*)alloc((size_t)32 * 512 * 256 * 4);

  if (cur > ws_size){
    float code = -1000.f - (float)(ws_size >> 20);
    kfb<<<(out_size + 255) / 256, 256, 0, stream>>>(out, out_size, code);
    return;
  }

  // bf16 weight casts (left half of w1; full w2)
  kcast_bf<<<(128 * 64 + 255) / 256, 256, 0, stream>>>(l0w1, 128, 64, 128, 0, w1bf1);
  kcast_bf<<<(128 * 128 + 255) / 256, 256, 0, stream>>>(l0w2, 128, 128, 128, 0, w2bf1);
  kcast_bf<<<(256 * 128 + 255) / 256, 256, 0, stream>>>(l1w1, 256, 128, 256, 0, w1bf2);
  kcast_bf<<<(256 * 256 + 255) / 256, 256, 0, stream>>>(l1w2, 256, 256, 256, 0, w2bf2);

  // stage A
  kA_stats<<<64, 256, 0, stream>>>(x, w_c1, g1, b1, sc1, sh1);
  kA_feat<<<128, 256, 0, stream>>>(x, w_c1, sc1, sh1, featT);

  // x_skip
  kxskip_pre<<<8192, 256, 0, stream>>>(featT, w_c2, xpre);
  kxskip_stats<<<1024, 256, 0, stream>>>(xpre, g2, b2, scSK, shSK);

  // stage 1 selections (DPP, full-VGPR)
  kfps<1024, 512, 1><<<32, 64, 0, stream>>>(x, x + 1024, x + 2048, 6144, fidx1, nxyz1);
  kknn<1024, 512><<<32 * 512 / 4, 256, 0, stream>>>(x, x + 1024, x + 2048, 6144, 1, nxyz1, knn1);

  // stage 1 local_op (MFMA)
  kgm<64, 128, 1024, 9, 0><<<16384, 256, 0, stream>>>(featT, knn1, fidx1, l0w1, w1bf1,
                                                      nullptr, nullptr, nullptr, nullptr, part, nullptr);
  kstats_part<128, 16384><<<128, 256, 0, stream>>>(part, l0g1, l0b1, scA1, shA1);
  kgm<64, 128, 1024, 9, 1><<<16384, 256, 0, stream>>>(featT, knn1, fidx1, l0w1, w1bf1,
                                                      scA1, shA1, w2bf1, l0g2, part, pooledPre);
  kstats_part<128, 16384><<<128, 256, 0, stream>>>(part, l0g2, l0b2, scA2, shA2);
  kpool_fin1<<<8192, 256, 0, stream>>>(pooledPre, scA2, shA2, f0feat);

  // stage 2 selections (DPP, full-VGPR)
  kfps<512, 256, 3><<<32, 64, 0, stream>>>(nxyz1, nxyz1 + 1, nxyz1 + 2, 1536, fidx2, nxyz2);
  kknn<512, 256><<<32 * 256 / 4, 256, 0, stream>>>(nxyz1, nxyz1 + 1, nxyz1 + 2, 1536, 3, nxyz2, knn2);

  // stage 2 local_op (MFMA)
  kgm<128, 256, 512, 8, 0><<<8192, 256, 0, stream>>>(f0feat, knn2, fidx2, l1w1, w1bf2,
                                                     nullptr, nullptr, nullptr, nullptr, part, nullptr);
  kstats_part<256, 8192><<<256, 256, 0, stream>>>(part, l1g1, l1b1, scC1, shC1);
  kgm<128, 256, 512, 8, 1><<<8192, 256, 0, stream>>>(f0feat, knn2, fidx2, l1w1, w1bf2,
                                                     scC1, shC1, w2bf2, l1g2, part, pooledPre);
  kstats_part<256, 8192><<<256, 256, 0, stream>>>(part, l1g2, l1b2, scC2, shC2);
  kpool_finT<<<8192, 256, 0, stream>>>(pooledPre, scC2, shC2, f1T);

  // final
  kfinal8<<<2048, 256, 0, stream>>>(f1T, xpre, scSK, shSK, wf, finpre);
  kstats_fin<<<512, 256, 0, stream>>>(finpre, gf, bfp, scF, shF);
  kapply<<<16384, 256, 0, stream>>>(finpre, scF, shF, out);
}

// Round 13
// 2487.396 us; speedup vs baseline: 1.4592x; 1.4592x over previous
//
#include <hip/hip_runtime.h>
#include <stdint.h>

typedef unsigned int u32;
typedef unsigned short u16;
typedef __attribute__((ext_vector_type(8))) short bf16x8;   // 8 bf16 = 4 VGPRs
typedef __attribute__((ext_vector_type(4))) float f32x4;

#define DEV __device__ __forceinline__
#define BN_EPS 1e-5f

DEV u16 f2bf(float f){ u32 x = __float_as_uint(f); return (u16)((x + 0x7FFFu + ((x >> 16) & 1u)) >> 16); }

// ---------------------------------------------------------------- DPP wave64 argmax/argmin reduce
template<int CTRL, int RMASK, bool MAXOP>
DEV void dpp_step(float& d, u32& i){
  int ds = __float_as_int(d);
  int is = (int)i;
  int dn_ = __builtin_amdgcn_update_dpp(ds, ds, CTRL, RMASK, 0xf, false);
  int in_ = __builtin_amdgcn_update_dpp(is, is, CTRL, RMASK, 0xf, false);
  float dn = __int_as_float(dn_);
  u32 ii = (u32)in_;
  bool take = MAXOP ? (dn > d || (dn == d && ii < i))
                    : (dn < d || (dn == d && ii < i));
  if (take){ d = dn; i = ii; }
}

template<bool MAXOP>
DEV u32 dpp_arg_reduce(float& d, u32& i){
  dpp_step<0x111, 0xf, MAXOP>(d, i);  // row_shr:1
  dpp_step<0x112, 0xf, MAXOP>(d, i);  // row_shr:2
  dpp_step<0x114, 0xf, MAXOP>(d, i);  // row_shr:4
  dpp_step<0x118, 0xf, MAXOP>(d, i);  // row_shr:8
  dpp_step<0x142, 0xa, MAXOP>(d, i);  // row_bcast15 -> rows 1,3
  dpp_step<0x143, 0xc, MAXOP>(d, i);  // row_bcast31 -> rows 2,3
  return (u32)__builtin_amdgcn_readlane((int)i, 63);
}

// ---------------------------------------------------------------- ws-too-small fallback
__global__ void kfb(float* out, int n, float code){
  int i = blockIdx.x * 256 + threadIdx.x;
  if (i < n) out[i] = (i == 0) ? code : 0.f;
}

// cast weights to bf16
__global__ void kcast_bf(const float* __restrict__ src, int rows, int cols, int srcStride, int colOff,
                         u16* __restrict__ dst){
  int i = blockIdx.x * 256 + threadIdx.x;
  if (i >= rows * cols) return;
  int r = i / cols, c = i - r * cols;
  dst[r * cols + c] = f2bf(src[r * srcStride + colOff + c]);
}

// ---------------------------------------------------------------- stage A: BN1 stats (deterministic)
__global__ __launch_bounds__(256) void kA_stats(const float* __restrict__ x, const float* __restrict__ w,
                                                const float* __restrict__ g, const float* __restrict__ b,
                                                float* __restrict__ sc, float* __restrict__ sh){
  int c = blockIdx.x, t = threadIdx.x;
  float wr[6];
#pragma unroll
  for (int j = 0; j < 6; ++j) wr[j] = w[c * 6 + j];
  float s = 0.f, ss = 0.f;
  for (int i = t; i < 32768; i += 256){
    int bb = i >> 10, n = i & 1023;
    const float* xb = x + bb * 6144 + n;
    float y = 0.f;
#pragma unroll
    for (int j = 0; j < 6; ++j) y += wr[j] * xb[j * 1024];
    s += y; ss += y * y;
  }
  __shared__ float rs[256], rq[256];
  rs[t] = s; rq[t] = ss; __syncthreads();
  for (int k = 128; k >= 1; k >>= 1){
    if (t < k){ rs[t] += rs[t + k]; rq[t] += rq[t + k]; }
    __syncthreads();
  }
  if (t == 0){
    float m = rs[0] * (1.f / 32768.f), e2 = rq[0] * (1.f / 32768.f);
    float var = e2 - m * m; if (var < 0.f) var = 0.f;
    float scv = g[c] * rsqrtf(var + BN_EPS);
    sc[c] = scv; sh[c] = b[c] - m * scv;
  }
}

// stage A apply -> featT f32 [b][n][64]
__global__ __launch_bounds__(256) void kA_feat(const float* __restrict__ x, const float* __restrict__ w,
                                               const float* __restrict__ sc, const float* __restrict__ sh,
                                               float* __restrict__ featT){
  int b = blockIdx.x >> 2, t = threadIdx.x;
  int n = ((blockIdx.x & 3) << 8) + t;
  __shared__ float wl[384], scl[64], shl[64];
  for (int u = t; u < 384; u += 256) wl[u] = w[u];
  if (t < 64){ scl[t] = sc[t]; shl[t] = sh[t]; }
  __syncthreads();
  float v[6];
  const float* xb = x + b * 6144 + n;
#pragma unroll
  for (int j = 0; j < 6; ++j) v[j] = xb[j * 1024];
  float* row = featT + ((size_t)b * 1024 + n) * 64;
#pragma unroll
  for (int c = 0; c < 64; ++c){
    float y = 0.f;
#pragma unroll
    for (int j = 0; j < 6; ++j) y += wl[c * 6 + j] * v[j];
    y = scl[c] * y + shl[c];
    row[c] = fmaxf(y, 0.f);
  }
}

// ---------------------------------------------------------------- x_skip pre-act f32 [b][1024][256]
__global__ __launch_bounds__(256) void kxskip_pre(const float* __restrict__ featT, const float* __restrict__ w2,
                                                  float* __restrict__ xpre){
  int b = blockIdx.x >> 8, m = blockIdx.x & 255, t = threadIdx.x;
  __shared__ float row[64];
  if (t < 64) row[t] = featT[((size_t)b * 1024 + 4 * m) * 64 + t];
  __syncthreads();
#pragma unroll
  for (int rep = 0; rep < 4; ++rep){
    int o = rep * 256 + t;
    float acc = 0.f;
    const float* wr = w2 + (size_t)o * 64;
#pragma unroll
    for (int c = 0; c < 64; ++c) acc += wr[c] * row[c];
    xpre[((size_t)b * 1024 + o) * 256 + m] = acc;
  }
}

__global__ __launch_bounds__(256) void kxskip_stats(const float* __restrict__ xpre, const float* __restrict__ g,
                                                    const float* __restrict__ b, float* __restrict__ sc,
                                                    float* __restrict__ sh){
  int o = blockIdx.x, t = threadIdx.x;
  float s = 0.f, ss = 0.f;
  for (int i = t; i < 8192; i += 256){
    int bb = i >> 8, m = i & 255;
    float v = xpre[((size_t)bb * 1024 + o) * 256 + m];
    s += v; ss += v * v;
  }
  __shared__ float rs[256], rq[256];
  rs[t] = s; rq[t] = ss; __syncthreads();
  for (int k = 128; k >= 1; k >>= 1){
    if (t < k){ rs[t] += rs[t + k]; rq[t] += rq[t + k]; }
    __syncthreads();
  }
  if (t == 0){
    float m = rs[0] * (1.f / 8192.f), e2 = rq[0] * (1.f / 8192.f);
    float var = e2 - m * m; if (var < 0.f) var = 0.f;
    float scv = g[o] * rsqrtf(var + BN_EPS);
    sc[o] = scv; sh[o] = b[o] - m * scv;
  }
}

// ---------------------------------------------------------------- FPS: points in LDS, dd in regs, DPP argmax
// LDS layout: lane i reads [j*64+i] (stride-1 across lanes -> 2 lanes/bank, free);
// winner read sx[win] is wave-uniform -> broadcast. Only dd[PPL]+scalars in regs -> no spill.
template<int NPTS, int NSAMP, int PSTRIDE>
__global__ __launch_bounds__(64) void kfps(const float* __restrict__ px_, const float* __restrict__ py_,
                                           const float* __restrict__ pz_, int bstride,
                                           int* __restrict__ fidx, float* __restrict__ nxyz){
  constexpr int PPL = NPTS / 64;
  __shared__ float sx[NPTS], sy[NPTS], sz[NPTS];
  int b = blockIdx.x, lane = threadIdx.x;
  float dd[PPL];
#pragma unroll
  for (int j = 0; j < PPL; ++j){
    int p = j * 64 + lane;
    sx[p] = px_[(size_t)b * bstride + p * PSTRIDE];
    sy[p] = py_[(size_t)b * bstride + p * PSTRIDE];
    sz[p] = pz_[(size_t)b * bstride + p * PSTRIDE];
    dd[j] = 1e10f;
  }
  __syncthreads();
  float cx = sx[0], cy = sy[0], cz = sz[0];
  if (lane == 0){
    fidx[(size_t)b * NSAMP] = 0;
    nxyz[(size_t)b * NSAMP * 3 + 0] = cx;
    nxyz[(size_t)b * NSAMP * 3 + 1] = cy;
    nxyz[(size_t)b * NSAMP * 3 + 2] = cz;
  }
  for (int s = 1; s < NSAMP; ++s){
    float bd = -1.f; u32 bi = 0;
#pragma unroll
    for (int j = 0; j < PPL; ++j){
      int p = j * 64 + lane;
      float dx = __fsub_rn(sx[p], cx);
      float dy = __fsub_rn(sy[p], cy);
      float dz = __fsub_rn(sz[p], cz);
      float d = __fadd_rn(__fadd_rn(__fmul_rn(dx, dx), __fmul_rn(dy, dy)), __fmul_rn(dz, dz));
      float v = fminf(dd[j], d);
      dd[j] = v;
      if (v > bd){ bd = v; bi = (u32)p; }   // strict > keeps lowest j (np.argmax first-index)
    }
    u32 win = dpp_arg_reduce<true>(bd, bi);
    cx = sx[win]; cy = sy[win]; cz = sz[win];   // uniform LDS broadcast
    if (lane == 0){
      fidx[(size_t)b * NSAMP + s] = (int)win;
      nxyz[((size_t)b * NSAMP + s) * 3 + 0] = cx;
      nxyz[((size_t)b * NSAMP + s) * 3 + 1] = cy;
      nxyz[((size_t)b * NSAMP + s) * 3 + 2] = cz;
    }
  }
}

// ---------------------------------------------------------------- kNN: DPP argmin, 4 waves/block
// kp[j] is invariantly j*64+lane -> recomputed, only kd[PPL] in regs -> no spill
template<int NPTS, int SOUT>
__global__ __launch_bounds__(256) void kknn(const float* __restrict__ px_, const float* __restrict__ py_,
                                            const float* __restrict__ pz_, int bstride, int pstride,
                                            const float* __restrict__ cxyz, int* __restrict__ knn){
  constexpr int PPL = NPTS / 64;
  int wid = blockIdx.x * 4 + (threadIdx.x >> 6);
  int lane = threadIdx.x & 63;
  int b = wid / SOUT, s = wid - b * SOUT;
  const float* cb = cxyz + ((size_t)b * SOUT + s) * 3;
  float cx = cb[0], cy = cb[1], cz = cb[2];
  float csq = __fadd_rn(__fadd_rn(__fmul_rn(cx, cx), __fmul_rn(cy, cy)), __fmul_rn(cz, cz));
  float kd[PPL];
#pragma unroll
  for (int j = 0; j < PPL; ++j){
    int p = j * 64 + lane;
    float xx = px_[(size_t)b * bstride + p * pstride];
    float yy = py_[(size_t)b * bstride + p * pstride];
    float zz = pz_[(size_t)b * bstride + p * pstride];
    float psq = __fadd_rn(__fadd_rn(__fmul_rn(xx, xx), __fmul_rn(yy, yy)), __fmul_rn(zz, zz));
    float dot = __fadd_rn(__fadd_rn(__fmul_rn(cx, xx), __fmul_rn(cy, yy)), __fmul_rn(cz, zz));
    kd[j] = __fsub_rn(__fadd_rn(csq, psq), __fmul_rn(2.f, dot));
  }
  int* outp = knn + ((size_t)b * SOUT + s) * 32;
  for (int k = 0; k < 32; ++k){
    float bd = kd[0]; u32 bi = (u32)lane;
#pragma unroll
    for (int j = 1; j < PPL; ++j){
      u32 p = (u32)(j * 64 + lane);
      if (kd[j] < bd){ bd = kd[j]; bi = p; }   // strict < keeps lowest j
    }
    u32 win = dpp_arg_reduce<false>(bd, bi);
    if (lane == 0) outp[k] = (int)win;
#pragma unroll
    for (int j = 0; j < PPL; ++j) if ((u32)(j * 64 + lane) == win) kd[j] = 3e38f;
  }
}

// ---------------------------------------------------------------- local_op via MFMA (unchanged)
template<int CIN, int C, int NPTSRC, int SLOG, int FULL>
__global__ __launch_bounds__(256) void kgm(const float* __restrict__ featSrc, const int* __restrict__ knnIdx,
                                           const int* __restrict__ fidx, const float* __restrict__ w1f,
                                           const u16* __restrict__ w1bf,
                                           const float* __restrict__ sc1g, const float* __restrict__ sh1g,
                                           const u16* __restrict__ w2bf, const float* __restrict__ gp,
                                           float* __restrict__ part, float* __restrict__ pooledPre){
  constexpr int MT  = C / 64;
  constexpr int KS1 = CIN / 32;
  constexpr int KS2 = C / 32;
  constexpr int P1  = CIN + 8;
  constexpr int P2  = C + 8;
  int g = blockIdx.x, t = threadIdx.x, b = g >> SLOG;
  int l = t & 63, wv = t >> 6;
  int lg = l >> 4, ln = l & 15;

  __shared__ int   idxs[32];
  __shared__ float cen[CIN];
  __shared__ float bias[C];
  __shared__ float sc1s[FULL ? C : 1], sh1s[FULL ? C : 1];
  __shared__ u16   gsT[32][P1];
  __shared__ u16   act2[FULL ? 32 : 1][FULL ? P2 : 1];

  if (t < 32) idxs[t] = knnIdx[(size_t)g * 32 + t];
  for (int u = t; u < CIN; u += 256) cen[u] = featSrc[((size_t)(b * NPTSRC + fidx[g])) * CIN + u];
  if (FULL && t < C){ sc1s[t] = sc1g[t]; sh1s[t] = sh1g[t]; }
  __syncthreads();

  for (int u = t; u < 32 * CIN / 4; u += 256){
    int k = u & 31, c4 = u >> 5;
    float4 v = *(const float4*)(featSrc + ((size_t)(b * NPTSRC + idxs[k])) * CIN + c4 * 4);
    u16 b0 = f2bf(v.x - cen[c4 * 4 + 0]), b1 = f2bf(v.y - cen[c4 * 4 + 1]);
    u16 b2 = f2bf(v.z - cen[c4 * 4 + 2]), b3 = f2bf(v.w - cen[c4 * 4 + 3]);
    *(uint2*)&gsT[k][c4 * 4] = make_uint2((u32)b0 | ((u32)b1 << 16), (u32)b2 | ((u32)b3 << 16));
  }
  if (t < C){
    const float* wr = w1f + (size_t)t * (2 * CIN) + CIN;
    float bs = 0.f;
#pragma unroll 4
    for (int c = 0; c < CIN; ++c) bs += wr[c] * cen[c];
    bias[t] = bs;
  }
  __syncthreads();

  f32x4 acc[MT][2];
#pragma unroll
  for (int mt = 0; mt < MT; ++mt){ acc[mt][0] = (f32x4)0.f; acc[mt][1] = (f32x4)0.f; }
#pragma unroll
  for (int ks = 0; ks < KS1; ++ks){
    int c0 = ks * 32 + lg * 8;
    bf16x8 bfr0 = *(const bf16x8*)&gsT[ln][c0];
    bf16x8 bfr1 = *(const bf16x8*)&gsT[16 + ln][c0];
#pragma unroll
    for (int mt = 0; mt < MT; ++mt){
      int o0 = wv * (C / 4) + mt * 16;
      bf16x8 afr = *(const bf16x8*)(w1bf + (size_t)(o0 + ln) * CIN + c0);
      acc[mt][0] = __builtin_amdgcn_mfma_f32_16x16x32_bf16(afr, bfr0, acc[mt][0], 0, 0, 0);
      acc[mt][1] = __builtin_amdgcn_mfma_f32_16x16x32_bf16(afr, bfr1, acc[mt][1], 0, 0, 0);
    }
  }

  if (!FULL){
#pragma unroll
    for (int mt = 0; mt < MT; ++mt){
      int obase = wv * (C / 4) + mt * 16 + lg * 4;
#pragma unroll
      for (int j = 0; j < 4; ++j){
        float bv = bias[obase + j];
        float vA = acc[mt][0][j] + bv, vB = acc[mt][1][j] + bv;
        float s = vA + vB, ss = vA * vA + vB * vB;
#pragma unroll
        for (int mk = 1; mk < 16; mk <<= 1){ s += __shfl_xor(s, mk, 64); ss += __shfl_xor(ss, mk, 64); }
        if (ln == 0){
          part[((size_t)g * C + obase + j) * 2 + 0] = s;
          part[((size_t)g * C + obase + j) * 2 + 1] = ss;
        }
      }
    }
    return;
  }

#pragma unroll
  for (int mt = 0; mt < MT; ++mt){
    int obase = wv * (C / 4) + mt * 16 + lg * 4;
#pragma unroll
    for (int nt = 0; nt < 2; ++nt){
      u16 h[4];
#pragma unroll
      for (int j = 0; j < 4; ++j){
        int o = obase + j;
        float v = fmaxf(sc1s[o] * (acc[mt][nt][j] + bias[o]) + sh1s[o], 0.f);
        h[j] = f2bf(v);
      }
      *(uint2*)&act2[nt * 16 + ln][obase] =
          make_uint2((u32)h[0] | ((u32)h[1] << 16), (u32)h[2] | ((u32)h[3] << 16));
    }
  }
  __syncthreads();

#pragma unroll
  for (int mt = 0; mt < MT; ++mt){ acc[mt][0] = (f32x4)0.f; acc[mt][1] = (f32x4)0.f; }
#pragma unroll
  for (int ks = 0; ks < KS2; ++ks){
    int c0 = ks * 32 + lg * 8;
    bf16x8 bfr0 = *(const bf16x8*)&act2[ln][c0];
    bf16x8 bfr1 = *(const bf16x8*)&act2[16 + ln][c0];
#pragma unroll
    for (int mt = 0; mt < MT; ++mt){
      int o0 = wv * (C / 4) + mt * 16;
      bf16x8 afr = *(const bf16x8*)(w2bf + (size_t)(o0 + ln) * C + c0);
      acc[mt][0] = __builtin_amdgcn_mfma_f32_16x16x32_bf16(afr, bfr0, acc[mt][0], 0, 0, 0);
      acc[mt][1] = __builtin_amdgcn_mfma_f32_16x16x32_bf16(afr, bfr1, acc[mt][1], 0, 0, 0);
    }
  }

#pragma unroll
  for (int mt = 0; mt < MT; ++mt){
    int obase = wv * (C / 4) + mt * 16 + lg * 4;
#pragma unroll
    for (int j = 0; j < 4; ++j){
      float vA = acc[mt][0][j], vB = acc[mt][1][j];
      float s = vA + vB, ss = vA * vA + vB * vB;
      float mx = fmaxf(vA, vB), mn = fminf(vA, vB);
#pragma unroll
      for (int mk = 1; mk < 16; mk <<= 1){
        s += __shfl_xor(s, mk, 64); ss += __shfl_xor(ss, mk, 64);
        mx = fmaxf(mx, __shfl_xor(mx, mk, 64)); mn = fminf(mn, __shfl_xor(mn, mk, 64));
      }
      if (ln == 0){
        int o = obase + j;
        part[((size_t)g * C + o) * 2 + 0] = s;
        part[((size_t)g * C + o) * 2 + 1] = ss;
        pooledPre[(size_t)g * C + o] = (gp[o] >= 0.f) ? mx : mn;
      }
    }
  }
}

// reduce per-group partials -> BN scale/shift (deterministic)
template<int C, int NG>
__global__ __launch_bounds__(256) void kstats_part(const float* __restrict__ part, const float* __restrict__ g_,
                                                   const float* __restrict__ b_, float* __restrict__ sc,
                                                   float* __restrict__ sh){
  int o = blockIdx.x, t = threadIdx.x;
  float s = 0.f, ss = 0.f;
  for (int i = t; i < NG; i += 256){
    s  += part[((size_t)i * C + o) * 2 + 0];
    ss += part[((size_t)i * C + o) * 2 + 1];
  }
  __shared__ float rs[256], rq[256];
  rs[t] = s; rq[t] = ss; __syncthreads();
  for (int k = 128; k >= 1; k >>= 1){
    if (t < k){ rs[t] += rs[t + k]; rq[t] += rq[t + k]; }
    __syncthreads();
  }
  if (t == 0){
    const float inv_n = 1.f / (float)(NG * 32);
    float m = rs[0] * inv_n, e2 = rq[0] * inv_n;
    float var = e2 - m * m; if (var < 0.f) var = 0.f;
    float scv = g_[o] * rsqrtf(var + BN_EPS);
    sc[o] = scv; sh[o] = b_[o] - m * scv;
  }
}

// finalize pooled (stage1): f0feat f32 [b*512+s][128]
__global__ void kpool_fin1(const float* __restrict__ pooledPre, const float* __restrict__ sc,
                           const float* __restrict__ sh, float* __restrict__ f0feat){
  int i = blockIdx.x * 256 + threadIdx.x;
  if (i >= 16384 * 128) return;
  int o = i & 127;
  float v = sc[o] * pooledPre[i] + sh[o];
  f0feat[i] = fmaxf(v, 0.f);
}

// finalize pooled (stage2): f1T f32 [b][c][s]
__global__ void kpool_finT(const float* __restrict__ pooledPre, const float* __restrict__ sc,
                           const float* __restrict__ sh, float* __restrict__ f1T){
  int i = blockIdx.x * 256 + threadIdx.x;
  if (i >= 8192 * 256) return;
  int gg = i >> 8, o = i & 255;
  int b = gg >> 8, s = gg & 255;
  float v = sc[o] * pooledPre[i] + sh[o];
  f1T[((size_t)(b * 256 + o)) * 256 + s] = fmaxf(v, 0.f);
}

// ---------------------------------------------------------------- final GEMM: block = (b, 8-o tile), thread = m
__global__ __launch_bounds__(256) void kfinal8(const float* __restrict__ f1T, const float* __restrict__ xpre,
                                               const float* __restrict__ scS, const float* __restrict__ shS,
                                               const float* __restrict__ wf, float* __restrict__ finpre){
  int b = blockIdx.x >> 6, ot = blockIdx.x & 63, m = threadIdx.x;
  int o0 = ot * 8;
  const float* wb = wf + (size_t)o0 * 1280;
  float acc[8];
#pragma unroll
  for (int j = 0; j < 8; ++j) acc[j] = 0.f;
  const float* fb = f1T + (size_t)b * 256 * 256 + m;
  for (int k = 0; k < 256; ++k){
    float v = fb[(size_t)k * 256];
#pragma unroll
    for (int j = 0; j < 8; ++j) acc[j] = fmaf(wb[(size_t)j * 1280 + k], v, acc[j]);
  }
  const float* xb = xpre + (size_t)b * 1024 * 256 + m;
  for (int k = 0; k < 1024; ++k){
    float xv = xb[(size_t)k * 256];
    float v = fmaxf(scS[k] * xv + shS[k], 0.f);
#pragma unroll
    for (int j = 0; j < 8; ++j) acc[j] = fmaf(wb[(size_t)j * 1280 + 256 + k], v, acc[j]);
  }
#pragma unroll
  for (int j = 0; j < 8; ++j)
    finpre[((size_t)b * 512 + o0 + j) * 256 + m] = acc[j];
}

__global__ __launch_bounds__(256) void kstats_fin(const float* __restrict__ finpre, const float* __restrict__ g,
                                                  const float* __restrict__ b, float* __restrict__ sc,
                                                  float* __restrict__ sh){
  int o = blockIdx.x, t = threadIdx.x;
  float s = 0.f, ss = 0.f;
  for (int i = t; i < 8192; i += 256){
    int bb = i >> 8, m = i & 255;
    float v = finpre[((size_t)bb * 512 + o) * 256 + m];
    s += v; ss += v * v;
  }
  __shared__ float rs[256], rq[256];
  rs[t] = s; rq[t] = ss; __syncthreads();
  for (int k = 128; k >= 1; k >>= 1){
    if (t < k){ rs[t] += rs[t + k]; rq[t] += rq[t + k]; }
    __syncthreads();
  }
  if (t == 0){
    float m = rs[0] * (1.f / 8192.f), e2 = rq[0] * (1.f / 8192.f);
    float var = e2 - m * m; if (var < 0.f) var = 0.f;
    float scv = g[o] * rsqrtf(var + BN_EPS);
    sc[o] = scv; sh[o] = b[o] - m * scv;
  }
}

__global__ void kapply(const float* __restrict__ finpre, const float* __restrict__ sc,
                       const float* __restrict__ sh, float* __restrict__ out){
  int i = blockIdx.x * 256 + threadIdx.x;
  if (i >= 32 * 512 * 256) return;
  int o = (i >> 8) & 511;
  float v = sc[o] * finpre[i] + sh[o];
  out[i] = v > 0.f ? v : 0.2f * v;
}

// ================================================================ host
extern "C" void kernel_launch(void* const* d_in, const int* in_sizes, int n_in,
                              void* d_out, int out_size, void* d_ws, size_t ws_size,
                              hipStream_t stream){
  const float* x    = (const float*)d_in[0];
  const float* w_c1 = (const float*)d_in[1];
  const float* g1   = (const float*)d_in[2];
  const float* b1   = (const float*)d_in[3];
  const float* w_c2 = (const float*)d_in[4];
  const float* g2   = (const float*)d_in[5];
  const float* b2   = (const float*)d_in[6];
  const float* l0w1 = (const float*)d_in[7];
  const float* l0g1 = (const float*)d_in[8];
  const float* l0b1 = (const float*)d_in[9];
  const float* l0w2 = (const float*)d_in[10];
  const float* l0g2 = (const float*)d_in[11];
  const float* l0b2 = (const float*)d_in[12];
  const float* l1w1 = (const float*)d_in[13];
  const float* l1g1 = (const float*)d_in[14];
  const float* l1b1 = (const float*)d_in[15];
  const float* l1w2 = (const float*)d_in[16];
  const float* l1g2 = (const float*)d_in[17];
  const float* l1b2 = (const float*)d_in[18];
  const float* wf   = (const float*)d_in[19];
  const float* gf   = (const float*)d_in[20];
  const float* bfp  = (const float*)d_in[21];
  float* out = (float*)d_out;

  char* ws = (char*)d_ws;
  size_t cur = 0;
  auto alloc = [&](size_t bytes) -> char* {
    char* p = ws + cur;
    cur += (bytes + 255) & ~(size_t)255;
    return p;
  };
  float* sc1  = (float*)alloc(64 * 4);    float* sh1  = (float*)alloc(64 * 4);
  float* scSK = (float*)alloc(1024 * 4);  float* shSK = (float*)alloc(1024 * 4);
  float* scA1 = (float*)alloc(128 * 4);   float* shA1 = (float*)alloc(128 * 4);
  float* scA2 = (float*)alloc(128 * 4);   float* shA2 = (float*)alloc(128 * 4);
  float* scC1 = (float*)alloc(256 * 4);   float* shC1 = (float*)alloc(256 * 4);
  float* scC2 = (float*)alloc(256 * 4);   float* shC2 = (float*)alloc(256 * 4);
  float* scF  = (float*)alloc(512 * 4);   float* shF  = (float*)alloc(512 * 4);
  u16* w1bf1 = (u16*)alloc((size_t)128 * 64 * 2);
  u16* w2bf1 = (u16*)alloc((size_t)128 * 128 * 2);
  u16* w1bf2 = (u16*)alloc((size_t)256 * 128 * 2);
  u16* w2bf2 = (u16*)alloc((size_t)256 * 256 * 2);
  float* featT  = (float*)alloc((size_t)32 * 1024 * 64 * 4);
  float* xpre   = (float*)alloc((size_t)32 * 1024 * 256 * 4);
  int*   fidx1  = (int*)  alloc((size_t)32 * 512 * 4);
  float* nxyz1  = (float*)alloc((size_t)32 * 512 * 3 * 4);
  int*   knn1   = (int*)  alloc((size_t)32 * 512 * 32 * 4);
  int*   fidx2  = (int*)  alloc((size_t)32 * 256 * 4);
  float* nxyz2  = (float*)alloc((size_t)32 * 256 * 3 * 4);
  int*   knn2   = (int*)  alloc((size_t)32 * 256 * 32 * 4);
  float* part   = (float*)alloc((size_t)16384 * 128 * 2 * 4);  // == 8192*256*2, reused by stage 2
  float* pooledPre = (float*)alloc((size_t)16384 * 128 * 4);   // == 8192*256, reused by stage 2
  float* f0feat = (float*)alloc((size_t)16384 * 128 * 4);
  float* f1T    = (float*)alloc((size_t)32 * 256 * 256 * 4);
  float* finpre = (float*)alloc((size_t)32 * 512 * 256 * 4);

  if (cur > ws_size){
    float code = -1000.f - (float)(ws_size >> 20);
    kfb<<<(out_size + 255) / 256, 256, 0, stream>>>(out, out_size, code);
    return;
  }

  // bf16 weight casts (left half of w1; full w2)
  kcast_bf<<<(128 * 64 + 255) / 256, 256, 0, stream>>>(l0w1, 128, 64, 128, 0, w1bf1);
  kcast_bf<<<(128 * 128 + 255) / 256, 256, 0, stream>>>(l0w2, 128, 128, 128, 0, w2bf1);
  kcast_bf<<<(256 * 128 + 255) / 256, 256, 0, stream>>>(l1w1, 256, 128, 256, 0, w1bf2);
  kcast_bf<<<(256 * 256 + 255) / 256, 256, 0, stream>>>(l1w2, 256, 256, 256, 0, w2bf2);

  // stage A
  kA_stats<<<64, 256, 0, stream>>>(x, w_c1, g1, b1, sc1, sh1);
  kA_feat<<<128, 256, 0, stream>>>(x, w_c1, sc1, sh1, featT);

  // x_skip
  kxskip_pre<<<8192, 256, 0, stream>>>(featT, w_c2, xpre);
  kxskip_stats<<<1024, 256, 0, stream>>>(xpre, g2, b2, scSK, shSK);

  // stage 1 selections (LDS-staged FPS + DPP)
  kfps<1024, 512, 1><<<32, 64, 0, stream>>>(x, x + 1024, x + 2048, 6144, fidx1, nxyz1);
  kknn<1024, 512><<<32 * 512 / 4, 256, 0, stream>>>(x, x + 1024, x + 2048, 6144, 1, nxyz1, knn1);

  // stage 1 local_op (MFMA)
  kgm<64, 128, 1024, 9, 0><<<16384, 256, 0, stream>>>(featT, knn1, fidx1, l0w1, w1bf1,
                                                      nullptr, nullptr, nullptr, nullptr, part, nullptr);
  kstats_part<128, 16384><<<128, 256, 0, stream>>>(part, l0g1, l0b1, scA1, shA1);
  kgm<64, 128, 1024, 9, 1><<<16384, 256, 0, stream>>>(featT, knn1, fidx1, l0w1, w1bf1,
                                                      scA1, shA1, w2bf1, l0g2, part, pooledPre);
  kstats_part<128, 16384><<<128, 256, 0, stream>>>(part, l0g2, l0b2, scA2, shA2);
  kpool_fin1<<<8192, 256, 0, stream>>>(pooledPre, scA2, shA2, f0feat);

  // stage 2 selections
  kfps<512, 256, 3><<<32, 64, 0, stream>>>(nxyz1, nxyz1 + 1, nxyz1 + 2, 1536, fidx2, nxyz2);
  kknn<512, 256><<<32 * 256 / 4, 256, 0, stream>>>(nxyz1, nxyz1 + 1, nxyz1 + 2, 1536, 3, nxyz2, knn2);

  // stage 2 local_op (MFMA)
  kgm<128, 256, 512, 8, 0><<<8192, 256, 0, stream>>>(f0feat, knn2, fidx2, l1w1, w1bf2,
                                                     nullptr, nullptr, nullptr, nullptr, part, nullptr);
  kstats_part<256, 8192><<<256, 256, 0, stream>>>(part, l1g1, l1b1, scC1, shC1);
  kgm<128, 256, 512, 8, 1><<<8192, 256, 0, stream>>>(f0feat, knn2, fidx2, l1w1, w1bf2,
                                                     scC1, shC1, w2bf2, l1g2, part, pooledPre);
  kstats_part<256, 8192><<<256, 256, 0, stream>>>(part, l1g2, l1b2, scC2, shC2);
  kpool_finT<<<8192, 256, 0, stream>>>(pooledPre, scC2, shC2, f1T);

  // final
  kfinal8<<<2048, 256, 0, stream>>>(f1T, xpre, scSK, shSK, wf, finpre);
  kstats_fin<<<512, 256, 0, stream>>>(finpre, gf, bfp, scF, shF);
  kapply<<<16384, 256, 0, stream>>>(finpre, scF, shF, out);
}

// Round 14
// 2115.544 us; speedup vs baseline: 1.7156x; 1.1758x over previous
//
#include <hip/hip_runtime.h>
#include <stdint.h>

typedef unsigned int u32;
typedef unsigned short u16;
typedef __attribute__((ext_vector_type(8))) short bf16x8;   // 8 bf16 = 4 VGPRs
typedef __attribute__((ext_vector_type(4))) float f32x4;

#define DEV __device__ __forceinline__
#define BN_EPS 1e-5f

DEV u16 f2bf(float f){ u32 x = __float_as_uint(f); return (u16)((x + 0x7FFFu + ((x >> 16) & 1u)) >> 16); }

// ---------------------------------------------------------------- DPP wave64 argmax/argmin reduce
template<int CTRL, int RMASK, bool MAXOP>
DEV void dpp_step(float& d, u32& i){
  int ds = __float_as_int(d);
  int is = (int)i;
  int dn_ = __builtin_amdgcn_update_dpp(ds, ds, CTRL, RMASK, 0xf, false);
  int in_ = __builtin_amdgcn_update_dpp(is, is, CTRL, RMASK, 0xf, false);
  float dn = __int_as_float(dn_);
  u32 ii = (u32)in_;
  bool take = MAXOP ? (dn > d || (dn == d && ii < i))
                    : (dn < d || (dn == d && ii < i));
  if (take){ d = dn; i = ii; }
}

template<bool MAXOP>
DEV u32 dpp_arg_reduce(float& d, u32& i){
  dpp_step<0x111, 0xf, MAXOP>(d, i);  // row_shr:1
  dpp_step<0x112, 0xf, MAXOP>(d, i);  // row_shr:2
  dpp_step<0x114, 0xf, MAXOP>(d, i);  // row_shr:4
  dpp_step<0x118, 0xf, MAXOP>(d, i);  // row_shr:8
  dpp_step<0x142, 0xa, MAXOP>(d, i);  // row_bcast15 -> rows 1,3
  dpp_step<0x143, 0xc, MAXOP>(d, i);  // row_bcast31 -> rows 2,3
  return (u32)__builtin_amdgcn_readlane((int)i, 63);
}

// ---------------------------------------------------------------- ws-too-small fallback
__global__ void kfb(float* out, int n, float code){
  int i = blockIdx.x * 256 + threadIdx.x;
  if (i < n) out[i] = (i == 0) ? code : 0.f;
}

// cast weights to bf16
__global__ void kcast_bf(const float* __restrict__ src, int rows, int cols, int srcStride, int colOff,
                         u16* __restrict__ dst){
  int i = blockIdx.x * 256 + threadIdx.x;
  if (i >= rows * cols) return;
  int r = i / cols, c = i - r * cols;
  dst[r * cols + c] = f2bf(src[r * srcStride + colOff + c]);
}

// ---------------------------------------------------------------- stage A: BN1 stats (deterministic)
__global__ __launch_bounds__(256) void kA_stats(const float* __restrict__ x, const float* __restrict__ w,
                                                const float* __restrict__ g, const float* __restrict__ b,
                                                float* __restrict__ sc, float* __restrict__ sh){
  int c = blockIdx.x, t = threadIdx.x;
  float wr[6];
#pragma unroll
  for (int j = 0; j < 6; ++j) wr[j] = w[c * 6 + j];
  float s = 0.f, ss = 0.f;
  for (int i = t; i < 32768; i += 256){
    int bb = i >> 10, n = i & 1023;
    const float* xb = x + bb * 6144 + n;
    float y = 0.f;
#pragma unroll
    for (int j = 0; j < 6; ++j) y += wr[j] * xb[j * 1024];
    s += y; ss += y * y;
  }
  __shared__ float rs[256], rq[256];
  rs[t] = s; rq[t] = ss; __syncthreads();
  for (int k = 128; k >= 1; k >>= 1){
    if (t < k){ rs[t] += rs[t + k]; rq[t] += rq[t + k]; }
    __syncthreads();
  }
  if (t == 0){
    float m = rs[0] * (1.f / 32768.f), e2 = rq[0] * (1.f / 32768.f);
    float var = e2 - m * m; if (var < 0.f) var = 0.f;
    float scv = g[c] * rsqrtf(var + BN_EPS);
    sc[c] = scv; sh[c] = b[c] - m * scv;
  }
}

// stage A apply -> featT f32 [b][n][64]
__global__ __launch_bounds__(256) void kA_feat(const float* __restrict__ x, const float* __restrict__ w,
                                               const float* __restrict__ sc, const float* __restrict__ sh,
                                               float* __restrict__ featT){
  int b = blockIdx.x >> 2, t = threadIdx.x;
  int n = ((blockIdx.x & 3) << 8) + t;
  __shared__ float wl[384], scl[64], shl[64];
  for (int u = t; u < 384; u += 256) wl[u] = w[u];
  if (t < 64){ scl[t] = sc[t]; shl[t] = sh[t]; }
  __syncthreads();
  float v[6];
  const float* xb = x + b * 6144 + n;
#pragma unroll
  for (int j = 0; j < 6; ++j) v[j] = xb[j * 1024];
  float* row = featT + ((size_t)b * 1024 + n) * 64;
#pragma unroll
  for (int c = 0; c < 64; ++c){
    float y = 0.f;
#pragma unroll
    for (int j = 0; j < 6; ++j) y += wl[c * 6 + j] * v[j];
    y = scl[c] * y + shl[c];
    row[c] = fmaxf(y, 0.f);
  }
}

// ---------------------------------------------------------------- x_skip pre-act f32 [b][1024][256]
// block = (b, 64-o tile); threads = m -> coalesced stores (fixes R13's 8x write amplification)
__global__ __launch_bounds__(256) void kxskip_pre(const float* __restrict__ featT, const float* __restrict__ w2,
                                                  float* __restrict__ xpre){
  int b = blockIdx.x >> 4, ot = blockIdx.x & 15, m = threadIdx.x;
  __shared__ float w2s[64][65];
  for (int u = threadIdx.x; u < 64 * 64; u += 256){
    int o = u >> 6, c = u & 63;
    w2s[o][c] = w2[(size_t)(ot * 64 + o) * 64 + c];
  }
  __syncthreads();
  float feat[64];
  const float* fr = featT + ((size_t)b * 1024 + 4 * m) * 64;
#pragma unroll
  for (int c = 0; c < 64; ++c) feat[c] = fr[c];
  float* xb = xpre + ((size_t)b * 1024 + ot * 64) * 256 + m;
  for (int o = 0; o < 64; ++o){
    float acc = 0.f;
#pragma unroll
    for (int c = 0; c < 64; ++c) acc += w2s[o][c] * feat[c];
    xb[(size_t)o * 256] = acc;
  }
}

__global__ __launch_bounds__(256) void kxskip_stats(const float* __restrict__ xpre, const float* __restrict__ g,
                                                    const float* __restrict__ b, float* __restrict__ sc,
                                                    float* __restrict__ sh){
  int o = blockIdx.x, t = threadIdx.x;
  float s = 0.f, ss = 0.f;
  for (int i = t; i < 8192; i += 256){
    int bb = i >> 8, m = i & 255;
    float v = xpre[((size_t)bb * 1024 + o) * 256 + m];
    s += v; ss += v * v;
  }
  __shared__ float rs[256], rq[256];
  rs[t] = s; rq[t] = ss; __syncthreads();
  for (int k = 128; k >= 1; k >>= 1){
    if (t < k){ rs[t] += rs[t + k]; rq[t] += rq[t + k]; }
    __syncthreads();
  }
  if (t == 0){
    float m = rs[0] * (1.f / 8192.f), e2 = rq[0] * (1.f / 8192.f);
    float var = e2 - m * m; if (var < 0.f) var = 0.f;
    float scv = g[o] * rsqrtf(var + BN_EPS);
    sc[o] = scv; sh[o] = b[o] - m * scv;
  }
}

// ---------------------------------------------------------------- FPS: points in LDS, dd in regs, DPP argmax
template<int NPTS, int NSAMP, int PSTRIDE>
__global__ __launch_bounds__(64) void kfps(const float* __restrict__ px_, const float* __restrict__ py_,
                                           const float* __restrict__ pz_, int bstride,
                                           int* __restrict__ fidx, float* __restrict__ nxyz){
  constexpr int PPL = NPTS / 64;
  __shared__ float sx[NPTS], sy[NPTS], sz[NPTS];
  int b = blockIdx.x, lane = threadIdx.x;
  float dd[PPL];
#pragma unroll
  for (int j = 0; j < PPL; ++j){
    int p = j * 64 + lane;
    sx[p] = px_[(size_t)b * bstride + p * PSTRIDE];
    sy[p] = py_[(size_t)b * bstride + p * PSTRIDE];
    sz[p] = pz_[(size_t)b * bstride + p * PSTRIDE];
    dd[j] = 1e10f;
  }
  __syncthreads();
  float cx = sx[0], cy = sy[0], cz = sz[0];
  if (lane == 0){
    fidx[(size_t)b * NSAMP] = 0;
    nxyz[(size_t)b * NSAMP * 3 + 0] = cx;
    nxyz[(size_t)b * NSAMP * 3 + 1] = cy;
    nxyz[(size_t)b * NSAMP * 3 + 2] = cz;
  }
  for (int s = 1; s < NSAMP; ++s){
    float bd = -1.f; u32 bi = 0;
#pragma unroll
    for (int j = 0; j < PPL; ++j){
      int p = j * 64 + lane;
      float dx = __fsub_rn(sx[p], cx);
      float dy = __fsub_rn(sy[p], cy);
      float dz = __fsub_rn(sz[p], cz);
      float d = __fadd_rn(__fadd_rn(__fmul_rn(dx, dx), __fmul_rn(dy, dy)), __fmul_rn(dz, dz));
      float v = fminf(dd[j], d);
      dd[j] = v;
      if (v > bd){ bd = v; bi = (u32)p; }   // strict > keeps lowest j (np.argmax first-index)
    }
    u32 win = dpp_arg_reduce<true>(bd, bi);
    cx = sx[win]; cy = sy[win]; cz = sz[win];   // uniform LDS broadcast
    if (lane == 0){
      fidx[(size_t)b * NSAMP + s] = (int)win;
      nxyz[((size_t)b * NSAMP + s) * 3 + 0] = cx;
      nxyz[((size_t)b * NSAMP + s) * 3 + 1] = cy;
      nxyz[((size_t)b * NSAMP + s) * 3 + 2] = cz;
    }
  }
}

// ---------------------------------------------------------------- kNN: DPP argmin, 4 waves/block
template<int NPTS, int SOUT>
__global__ __launch_bounds__(256) void kknn(const float* __restrict__ px_, const float* __restrict__ py_,
                                            const float* __restrict__ pz_, int bstride, int pstride,
                                            const float* __restrict__ cxyz, int* __restrict__ knn){
  constexpr int PPL = NPTS / 64;
  int wid = blockIdx.x * 4 + (threadIdx.x >> 6);
  int lane = threadIdx.x & 63;
  int b = wid / SOUT, s = wid - b * SOUT;
  const float* cb = cxyz + ((size_t)b * SOUT + s) * 3;
  float cx = cb[0], cy = cb[1], cz = cb[2];
  float csq = __fadd_rn(__fadd_rn(__fmul_rn(cx, cx), __fmul_rn(cy, cy)), __fmul_rn(cz, cz));
  float kd[PPL];
#pragma unroll
  for (int j = 0; j < PPL; ++j){
    int p = j * 64 + lane;
    float xx = px_[(size_t)b * bstride + p * pstride];
    float yy = py_[(size_t)b * bstride + p * pstride];
    float zz = pz_[(size_t)b * bstride + p * pstride];
    float psq = __fadd_rn(__fadd_rn(__fmul_rn(xx, xx), __fmul_rn(yy, yy)), __fmul_rn(zz, zz));
    float dot = __fadd_rn(__fadd_rn(__fmul_rn(cx, xx), __fmul_rn(cy, yy)), __fmul_rn(cz, zz));
    kd[j] = __fsub_rn(__fadd_rn(csq, psq), __fmul_rn(2.f, dot));
  }
  int* outp = knn + ((size_t)b * SOUT + s) * 32;
  for (int k = 0; k < 32; ++k){
    float bd = kd[0]; u32 bi = (u32)lane;
#pragma unroll
    for (int j = 1; j < PPL; ++j){
      u32 p = (u32)(j * 64 + lane);
      if (kd[j] < bd){ bd = kd[j]; bi = p; }   // strict < keeps lowest j
    }
    u32 win = dpp_arg_reduce<false>(bd, bi);
    if (lane == 0) outp[k] = (int)win;
#pragma unroll
    for (int j = 0; j < PPL; ++j) if ((u32)(j * 64 + lane) == win) kd[j] = 3e38f;
  }
}

// ---------------------------------------------------------------- local_op via MFMA (unchanged)
template<int CIN, int C, int NPTSRC, int SLOG, int FULL>
__global__ __launch_bounds__(256) void kgm(const float* __restrict__ featSrc, const int* __restrict__ knnIdx,
                                           const int* __restrict__ fidx, const float* __restrict__ w1f,
                                           const u16* __restrict__ w1bf,
                                           const float* __restrict__ sc1g, const float* __restrict__ sh1g,
                                           const u16* __restrict__ w2bf, const float* __restrict__ gp,
                                           float* __restrict__ part, float* __restrict__ pooledPre){
  constexpr int MT  = C / 64;
  constexpr int KS1 = CIN / 32;
  constexpr int KS2 = C / 32;
  constexpr int P1  = CIN + 8;
  constexpr int P2  = C + 8;
  int g = blockIdx.x, t = threadIdx.x, b = g >> SLOG;
  int l = t & 63, wv = t >> 6;
  int lg = l >> 4, ln = l & 15;

  __shared__ int   idxs[32];
  __shared__ float cen[CIN];
  __shared__ float bias[C];
  __shared__ float sc1s[FULL ? C : 1], sh1s[FULL ? C : 1];
  __shared__ u16   gsT[32][P1];
  __shared__ u16   act2[FULL ? 32 : 1][FULL ? P2 : 1];

  if (t < 32) idxs[t] = knnIdx[(size_t)g * 32 + t];
  for (int u = t; u < CIN; u += 256) cen[u] = featSrc[((size_t)(b * NPTSRC + fidx[g])) * CIN + u];
  if (FULL && t < C){ sc1s[t] = sc1g[t]; sh1s[t] = sh1g[t]; }
  __syncthreads();

  for (int u = t; u < 32 * CIN / 4; u += 256){
    int k = u & 31, c4 = u >> 5;
    float4 v = *(const float4*)(featSrc + ((size_t)(b * NPTSRC + idxs[k])) * CIN + c4 * 4);
    u16 b0 = f2bf(v.x - cen[c4 * 4 + 0]), b1 = f2bf(v.y - cen[c4 * 4 + 1]);
    u16 b2 = f2bf(v.z - cen[c4 * 4 + 2]), b3 = f2bf(v.w - cen[c4 * 4 + 3]);
    *(uint2*)&gsT[k][c4 * 4] = make_uint2((u32)b0 | ((u32)b1 << 16), (u32)b2 | ((u32)b3 << 16));
  }
  if (t < C){
    const float* wr = w1f + (size_t)t * (2 * CIN) + CIN;
    float bs = 0.f;
#pragma unroll 4
    for (int c = 0; c < CIN; ++c) bs += wr[c] * cen[c];
    bias[t] = bs;
  }
  __syncthreads();

  f32x4 acc[MT][2];
#pragma unroll
  for (int mt = 0; mt < MT; ++mt){ acc[mt][0] = (f32x4)0.f; acc[mt][1] = (f32x4)0.f; }
#pragma unroll
  for (int ks = 0; ks < KS1; ++ks){
    int c0 = ks * 32 + lg * 8;
    bf16x8 bfr0 = *(const bf16x8*)&gsT[ln][c0];
    bf16x8 bfr1 = *(const bf16x8*)&gsT[16 + ln][c0];
#pragma unroll
    for (int mt = 0; mt < MT; ++mt){
      int o0 = wv * (C / 4) + mt * 16;
      bf16x8 afr = *(const bf16x8*)(w1bf + (size_t)(o0 + ln) * CIN + c0);
      acc[mt][0] = __builtin_amdgcn_mfma_f32_16x16x32_bf16(afr, bfr0, acc[mt][0], 0, 0, 0);
      acc[mt][1] = __builtin_amdgcn_mfma_f32_16x16x32_bf16(afr, bfr1, acc[mt][1], 0, 0, 0);
    }
  }

  if (!FULL){
#pragma unroll
    for (int mt = 0; mt < MT; ++mt){
      int obase = wv * (C / 4) + mt * 16 + lg * 4;
#pragma unroll
      for (int j = 0; j < 4; ++j){
        float bv = bias[obase + j];
        float vA = acc[mt][0][j] + bv, vB = acc[mt][1][j] + bv;
        float s = vA + vB, ss = vA * vA + vB * vB;
#pragma unroll
        for (int mk = 1; mk < 16; mk <<= 1){ s += __shfl_xor(s, mk, 64); ss += __shfl_xor(ss, mk, 64); }
        if (ln == 0){
          part[((size_t)g * C + obase + j) * 2 + 0] = s;
          part[((size_t)g * C + obase + j) * 2 + 1] = ss;
        }
      }
    }
    return;
  }

#pragma unroll
  for (int mt = 0; mt < MT; ++mt){
    int obase = wv * (C / 4) + mt * 16 + lg * 4;
#pragma unroll
    for (int nt = 0; nt < 2; ++nt){
      u16 h[4];
#pragma unroll
      for (int j = 0; j < 4; ++j){
        int o = obase + j;
        float v = fmaxf(sc1s[o] * (acc[mt][nt][j] + bias[o]) + sh1s[o], 0.f);
        h[j] = f2bf(v);
      }
      *(uint2*)&act2[nt * 16 + ln][obase] =
          make_uint2((u32)h[0] | ((u32)h[1] << 16), (u32)h[2] | ((u32)h[3] << 16));
    }
  }
  __syncthreads();

#pragma unroll
  for (int mt = 0; mt < MT; ++mt){ acc[mt][0] = (f32x4)0.f; acc[mt][1] = (f32x4)0.f; }
#pragma unroll
  for (int ks = 0; ks < KS2; ++ks){
    int c0 = ks * 32 + lg * 8;
    bf16x8 bfr0 = *(const bf16x8*)&act2[ln][c0];
    bf16x8 bfr1 = *(const bf16x8*)&act2[16 + ln][c0];
#pragma unroll
    for (int mt = 0; mt < MT; ++mt){
      int o0 = wv * (C / 4) + mt * 16;
      bf16x8 afr = *(const bf16x8*)(w2bf + (size_t)(o0 + ln) * C + c0);
      acc[mt][0] = __builtin_amdgcn_mfma_f32_16x16x32_bf16(afr, bfr0, acc[mt][0], 0, 0, 0);
      acc[mt][1] = __builtin_amdgcn_mfma_f32_16x16x32_bf16(afr, bfr1, acc[mt][1], 0, 0, 0);
    }
  }

#pragma unroll
  for (int mt = 0; mt < MT; ++mt){
    int obase = wv * (C / 4) + mt * 16 + lg * 4;
#pragma unroll
    for (int j = 0; j < 4; ++j){
      float vA = acc[mt][0][j], vB = acc[mt][1][j];
      float s = vA + vB, ss = vA * vA + vB * vB;
      float mx = fmaxf(vA, vB), mn = fminf(vA, vB);
#pragma unroll
      for (int mk = 1; mk < 16; mk <<= 1){
        s += __shfl_xor(s, mk, 64); ss += __shfl_xor(ss, mk, 64);
        mx = fmaxf(mx, __shfl_xor(mx, mk, 64)); mn = fminf(mn, __shfl_xor(mn, mk, 64));
      }
      if (ln == 0){
        int o = obase + j;
        part[((size_t)g * C + o) * 2 + 0] = s;
        part[((size_t)g * C + o) * 2 + 1] = ss;
        pooledPre[(size_t)g * C + o] = (gp[o] >= 0.f) ? mx : mn;
      }
    }
  }
}

// reduce per-group partials -> BN scale/shift (deterministic)
template<int C, int NG>
__global__ __launch_bounds__(256) void kstats_part(const float* __restrict__ part, const float* __restrict__ g_,
                                                   const float* __restrict__ b_, float* __restrict__ sc,
                                                   float* __restrict__ sh){
  int o = blockIdx.x, t = threadIdx.x;
  float s = 0.f, ss = 0.f;
  for (int i = t; i < NG; i += 256){
    s  += part[((size_t)i * C + o) * 2 + 0];
    ss += part[((size_t)i * C + o) * 2 + 1];
  }
  __shared__ float rs[256], rq[256];
  rs[t] = s; rq[t] = ss; __syncthreads();
  for (int k = 128; k >= 1; k >>= 1){
    if (t < k){ rs[t] += rs[t + k]; rq[t] += rq[t + k]; }
    __syncthreads();
  }
  if (t == 0){
    const float inv_n = 1.f / (float)(NG * 32);
    float m = rs[0] * inv_n, e2 = rq[0] * inv_n;
    float var = e2 - m * m; if (var < 0.f) var = 0.f;
    float scv = g_[o] * rsqrtf(var + BN_EPS);
    sc[o] = scv; sh[o] = b_[o] - m * scv;
  }
}

// finalize pooled (stage1): f0feat f32 [b*512+s][128]
__global__ void kpool_fin1(const float* __restrict__ pooledPre, const float* __restrict__ sc,
                           const float* __restrict__ sh, float* __restrict__ f0feat){
  int i = blockIdx.x * 256 + threadIdx.x;
  if (i >= 16384 * 128) return;
  int o = i & 127;
  float v = sc[o] * pooledPre[i] + sh[o];
  f0feat[i] = fmaxf(v, 0.f);
}

// finalize pooled (stage2): f1T f32 [b][c][s]
__global__ void kpool_finT(const float* __restrict__ pooledPre, const float* __restrict__ sc,
                           const float* __restrict__ sh, float* __restrict__ f1T){
  int i = blockIdx.x * 256 + threadIdx.x;
  if (i >= 8192 * 256) return;
  int gg = i >> 8, o = i & 255;
  int b = gg >> 8, s = gg & 255;
  float v = sc[o] * pooledPre[i] + sh[o];
  f1T[((size_t)(b * 256 + o)) * 256 + s] = fmaxf(v, 0.f);
}

// ---------------------------------------------------------------- final GEMM: block = (b, 8-o tile), thread = m
__global__ __launch_bounds__(256) void kfinal8(const float* __restrict__ f1T, const float* __restrict__ xpre,
                                               const float* __restrict__ scS, const float* __restrict__ shS,
                                               const float* __restrict__ wf, float* __restrict__ finpre){
  int b = blockIdx.x >> 6, ot = blockIdx.x & 63, m = threadIdx.x;
  int o0 = ot * 8;
  const float* wb = wf + (size_t)o0 * 1280;
  float acc[8];
#pragma unroll
  for (int j = 0; j < 8; ++j) acc[j] = 0.f;
  const float* fb = f1T + (size_t)b * 256 * 256 + m;
  for (int k = 0; k < 256; ++k){
    float v = fb[(size_t)k * 256];
#pragma unroll
    for (int j = 0; j < 8; ++j) acc[j] = fmaf(wb[(size_t)j * 1280 + k], v, acc[j]);
  }
  const float* xb = xpre + (size_t)b * 1024 * 256 + m;
  for (int k = 0; k < 1024; ++k){
    float xv = xb[(size_t)k * 256];
    float v = fmaxf(scS[k] * xv + shS[k], 0.f);
#pragma unroll
    for (int j = 0; j < 8; ++j) acc[j] = fmaf(wb[(size_t)j * 1280 + 256 + k], v, acc[j]);
  }
#pragma unroll
  for (int j = 0; j < 8; ++j)
    finpre[((size_t)b * 512 + o0 + j) * 256 + m] = acc[j];
}

__global__ __launch_bounds__(256) void kstats_fin(const float* __restrict__ finpre, const float* __restrict__ g,
                                                  const float* __restrict__ b, float* __restrict__ sc,
                                                  float* __restrict__ sh){
  int o = blockIdx.x, t = threadIdx.x;
  float s = 0.f, ss = 0.f;
  for (int i = t; i < 8192; i += 256){
    int bb = i >> 8, m = i & 255;
    float v = finpre[((size_t)bb * 512 + o) * 256 + m];
    s += v; ss += v * v;
  }
  __shared__ float rs[256], rq[256];
  rs[t] = s; rq[t] = ss; __syncthreads();
  for (int k = 128; k >= 1; k >>= 1){
    if (t < k){ rs[t] += rs[t + k]; rq[t] += rq[t + k]; }
    __syncthreads();
  }
  if (t == 0){
    float m = rs[0] * (1.f / 8192.f), e2 = rq[0] * (1.f / 8192.f);
    float var = e2 - m * m; if (var < 0.f) var = 0.f;
    float scv = g[o] * rsqrtf(var + BN_EPS);
    sc[o] = scv; sh[o] = b[o] - m * scv;
  }
}

__global__ void kapply(const float* __restrict__ finpre, const float* __restrict__ sc,
                       const float* __restrict__ sh, float* __restrict__ out){
  int i = blockIdx.x * 256 + threadIdx.x;
  if (i >= 32 * 512 * 256) return;
  int o = (i >> 8) & 511;
  float v = sc[o] * finpre[i] + sh[o];
  out[i] = v > 0.f ? v : 0.2f * v;
}

// ================================================================ host
extern "C" void kernel_launch(void* const* d_in, const int* in_sizes, int n_in,
                              void* d_out, int out_size, void* d_ws, size_t ws_size,
                              hipStream_t stream){
  const float* x    = (const float*)d_in[0];
  const float* w_c1 = (const float*)d_in[1];
  const float* g1   = (const float*)d_in[2];
  const float* b1   = (const float*)d_in[3];
  const float* w_c2 = (const float*)d_in[4];
  const float* g2   = (const float*)d_in[5];
  const float* b2   = (const float*)d_in[6];
  const float* l0w1 = (const float*)d_in[7];
  const float* l0g1 = (const float*)d_in[8];
  const float* l0b1 = (const float*)d_in[9];
  const float* l0w2 = (const float*)d_in[10];
  const float* l0g2 = (const float*)d_in[11];
  const float* l0b2 = (const float*)d_in[12];
  const float* l1w1 = (const float*)d_in[13];
  const float* l1g1 = (const float*)d_in[14];
  const float* l1b1 = (const float*)d_in[15];
  const float* l1w2 = (const float*)d_in[16];
  const float* l1g2 = (const float*)d_in[17];
  const float* l1b2 = (const float*)d_in[18];
  const float* wf   = (const float*)d_in[19];
  const float* gf   = (const float*)d_in[20];
  const float* bfp  = (const float*)d_in[21];
  float* out = (float*)d_out;

  char* ws = (char*)d_ws;
  size_t cur = 0;
  auto alloc = [&](size_t bytes) -> char* {
    char* p = ws + cur;
    cur += (bytes + 255) & ~(size_t)255;
    return p;
  };
  float* sc1  = (float*)alloc(64 * 4);    float* sh1  = (float*)alloc(64 * 4);
  float* scSK = (float*)alloc(1024 * 4);  float* shSK = (float*)alloc(1024 * 4);
  float* scA1 = (float*)alloc(128 * 4);   float* shA1 = (float*)alloc(128 * 4);
  float* scA2 = (float*)alloc(128 * 4);   float* shA2 = (float*)alloc(128 * 4);
  float* scC1 = (float*)alloc(256 * 4);   float* shC1 = (float*)alloc(256 * 4);
  float* scC2 = (float*)alloc(256 * 4);   float* shC2 = (float*)alloc(256 * 4);
  float* scF  = (float*)alloc(512 * 4);   float* shF  = (float*)alloc(512 * 4);
  u16* w1bf1 = (u16*)alloc((size_t)128 * 64 * 2);
  u16* w2bf1 = (u16*)alloc((size_t)128 * 128 * 2);
  u16* w1bf2 = (u16*)alloc((size_t)256 * 128 * 2);
  u16* w2bf2 = (u16*)alloc((size_t)256 * 256 * 2);
  float* featT  = (float*)alloc((size_t)32 * 1024 * 64 * 4);
  float* xpre   = (float*)alloc((size_t)32 * 1024 * 256 * 4);
  int*   fidx1  = (int*)  alloc((size_t)32 * 512 * 4);
  float* nxyz1  = (float*)alloc((size_t)32 * 512 * 3 * 4);
  int*   knn1   = (int*)  alloc((size_t)32 * 512 * 32 * 4);
  int*   fidx2  = (int*)  alloc((size_t)32 * 256 * 4);
  float* nxyz2  = (float*)alloc((size_t)32 * 256 * 3 * 4);
  int*   knn2   = (int*)  alloc((size_t)32 * 256 * 32 * 4);
  float* part   = (float*)alloc((size_t)16384 * 128 * 2 * 4);  // == 8192*256*2, reused by stage 2
  float* pooledPre = (float*)alloc((size_t)16384 * 128 * 4);   // == 8192*256, reused by stage 2
  float* f0feat = (float*)alloc((size_t)16384 * 128 * 4);
  float* f1T    = (float*)alloc((size_t)32 * 256 * 256 * 4);
  float* finpre = (float*)alloc((size_t)32 * 512 * 256 * 4);

  if (cur > ws_size){
    float code = -1000.f - (float)(ws_size >> 20);
    kfb<<<(out_size + 255) / 256, 256, 0, stream>>>(out, out_size, code);
    return;
  }

  // bf16 weight casts (left half of w1; full w2)
  kcast_bf<<<(128 * 64 + 255) / 256, 256, 0, stream>>>(l0w1, 128, 64, 128, 0, w1bf1);
  kcast_bf<<<(128 * 128 + 255) / 256, 256, 0, stream>>>(l0w2, 128, 128, 128, 0, w2bf1);
  kcast_bf<<<(256 * 128 + 255) / 256, 256, 0, stream>>>(l1w1, 256, 128, 256, 0, w1bf2);
  kcast_bf<<<(256 * 256 + 255) / 256, 256, 0, stream>>>(l1w2, 256, 256, 256, 0, w2bf2);

  // stage A
  kA_stats<<<64, 256, 0, stream>>>(x, w_c1, g1, b1, sc1, sh1);
  kA_feat<<<128, 256, 0, stream>>>(x, w_c1, sc1, sh1, featT);

  // x_skip (coalesced writes)
  kxskip_pre<<<512, 256, 0, stream>>>(featT, w_c2, xpre);
  kxskip_stats<<<1024, 256, 0, stream>>>(xpre, g2, b2, scSK, shSK);

  // stage 1 selections (LDS-staged FPS + DPP)
  kfps<1024, 512, 1><<<32, 64, 0, stream>>>(x, x + 1024, x + 2048, 6144, fidx1, nxyz1);
  kknn<1024, 512><<<32 * 512 / 4, 256, 0, stream>>>(x, x + 1024, x + 2048, 6144, 1, nxyz1, knn1);

  // stage 1 local_op (MFMA)
  kgm<64, 128, 1024, 9, 0><<<16384, 256, 0, stream>>>(featT, knn1, fidx1, l0w1, w1bf1,
                                                      nullptr, nullptr, nullptr, nullptr, part, nullptr);
  kstats_part<128, 16384><<<128, 256, 0, stream>>>(part, l0g1, l0b1, scA1, shA1);
  kgm<64, 128, 1024, 9, 1><<<16384, 256, 0, stream>>>(featT, knn1, fidx1, l0w1, w1bf1,
                                                      scA1, shA1, w2bf1, l0g2, part, pooledPre);
  kstats_part<128, 16384><<<128, 256, 0, stream>>>(part, l0g2, l0b2, scA2, shA2);
  kpool_fin1<<<8192, 256, 0, stream>>>(pooledPre, scA2, shA2, f0feat);

  // stage 2 selections
  kfps<512, 256, 3><<<32, 64, 0, stream>>>(nxyz1, nxyz1 + 1, nxyz1 + 2, 1536, fidx2, nxyz2);
  kknn<512, 256><<<32 * 256 / 4, 256, 0, stream>>>(nxyz1, nxyz1 + 1, nxyz1 + 2, 1536, 3, nxyz2, knn2);

  // stage 2 local_op (MFMA)
  kgm<128, 256, 512, 8, 0><<<8192, 256, 0, stream>>>(f0feat, knn2, fidx2, l1w1, w1bf2,
                                                     nullptr, nullptr, nullptr, nullptr, part, nullptr);
  kstats_part<256, 8192><<<256, 256, 0, stream>>>(part, l1g1, l1b1, scC1, shC1);
  kgm<128, 256, 512, 8, 1><<<8192, 256, 0, stream>>>(f0feat, knn2, fidx2, l1w1, w1bf2,
                                                     scC1, shC1, w2bf2, l1g2, part, pooledPre);
  kstats_part<256, 8192><<<256, 256, 0, stream>>>(part, l1g2, l1b2, scC2, shC2);
  kpool_finT<<<8192, 256, 0, stream>>>(pooledPre, scC2, shC2, f1T);

  // final
  kfinal8<<<2048, 256, 0, stream>>>(f1T, xpre, scSK, shSK, wf, finpre);
  kstats_fin<<<512, 256, 0, stream>>>(finpre, gf, bfp, scF, shF);
  kapply<<<16384, 256, 0, stream>>>(finpre, scF, shF, out);
}

// Round 15
// 1817.806 us; speedup vs baseline: 1.9966x; 1.1638x over previous
//
#include <hip/hip_runtime.h>
#include <stdint.h>

typedef unsigned int u32;
typedef unsigned short u16;
typedef __attribute__((ext_vector_type(8))) short bf16x8;   // 8 bf16 = 4 VGPRs
typedef __attribute__((ext_vector_type(4))) float f32x4;

#define DEV __device__ __forceinline__
#define BN_EPS 1e-5f

DEV float bf2f(u16 u){ return __uint_as_float(((u32)u) << 16); }
DEV u16 f2bf(float f){ u32 x = __float_as_uint(f); return (u16)((x + 0x7FFFu + ((x >> 16) & 1u)) >> 16); }

// ---------------------------------------------------------------- DPP wave64 argmax/argmin reduce
template<int CTRL, int RMASK, bool MAXOP>
DEV void dpp_step(float& d, u32& i){
  int ds = __float_as_int(d);
  int is = (int)i;
  int dn_ = __builtin_amdgcn_update_dpp(ds, ds, CTRL, RMASK, 0xf, false);
  int in_ = __builtin_amdgcn_update_dpp(is, is, CTRL, RMASK, 0xf, false);
  float dn = __int_as_float(dn_);
  u32 ii = (u32)in_;
  bool take = MAXOP ? (dn > d || (dn == d && ii < i))
                    : (dn < d || (dn == d && ii < i));
  if (take){ d = dn; i = ii; }
}

template<bool MAXOP>
DEV u32 dpp_arg_reduce(float& d, u32& i){
  dpp_step<0x111, 0xf, MAXOP>(d, i);
  dpp_step<0x112, 0xf, MAXOP>(d, i);
  dpp_step<0x114, 0xf, MAXOP>(d, i);
  dpp_step<0x118, 0xf, MAXOP>(d, i);
  dpp_step<0x142, 0xa, MAXOP>(d, i);
  dpp_step<0x143, 0xc, MAXOP>(d, i);
  return (u32)__builtin_amdgcn_readlane((int)i, 63);
}

// ---------------------------------------------------------------- ws-too-small fallback
__global__ void kfb(float* out, int n, float code){
  int i = blockIdx.x * 256 + threadIdx.x;
  if (i < n) out[i] = (i == 0) ? code : 0.f;
}

// cast weights to bf16
__global__ void kcast_bf(const float* __restrict__ src, int rows, int cols, int srcStride, int colOff,
                         u16* __restrict__ dst){
  int i = blockIdx.x * 256 + threadIdx.x;
  if (i >= rows * cols) return;
  int r = i / cols, c = i - r * cols;
  dst[r * cols + c] = f2bf(src[r * srcStride + colOff + c]);
}

// ---------------------------------------------------------------- stage A: BN1 stats (deterministic)
__global__ __launch_bounds__(256) void kA_stats(const float* __restrict__ x, const float* __restrict__ w,
                                                const float* __restrict__ g, const float* __restrict__ b,
                                                float* __restrict__ sc, float* __restrict__ sh){
  int c = blockIdx.x, t = threadIdx.x;
  float wr[6];
#pragma unroll
  for (int j = 0; j < 6; ++j) wr[j] = w[c * 6 + j];
  float s = 0.f, ss = 0.f;
  for (int i = t; i < 32768; i += 256){
    int bb = i >> 10, n = i & 1023;
    const float* xb = x + bb * 6144 + n;
    float y = 0.f;
#pragma unroll
    for (int j = 0; j < 6; ++j) y += wr[j] * xb[j * 1024];
    s += y; ss += y * y;
  }
  __shared__ float rs[256], rq[256];
  rs[t] = s; rq[t] = ss; __syncthreads();
  for (int k = 128; k >= 1; k >>= 1){
    if (t < k){ rs[t] += rs[t + k]; rq[t] += rq[t + k]; }
    __syncthreads();
  }
  if (t == 0){
    float m = rs[0] * (1.f / 32768.f), e2 = rq[0] * (1.f / 32768.f);
    float var = e2 - m * m; if (var < 0.f) var = 0.f;
    float scv = g[c] * rsqrtf(var + BN_EPS);
    sc[c] = scv; sh[c] = b[c] - m * scv;
  }
}

// stage A apply -> featT bf16 [b][n][64]
__global__ __launch_bounds__(256) void kA_feat(const float* __restrict__ x, const float* __restrict__ w,
                                               const float* __restrict__ sc, const float* __restrict__ sh,
                                               u16* __restrict__ featT){
  int b = blockIdx.x >> 2, t = threadIdx.x;
  int n = ((blockIdx.x & 3) << 8) + t;
  __shared__ float wl[384], scl[64], shl[64];
  for (int u = t; u < 384; u += 256) wl[u] = w[u];
  if (t < 64){ scl[t] = sc[t]; shl[t] = sh[t]; }
  __syncthreads();
  float v[6];
  const float* xb = x + b * 6144 + n;
#pragma unroll
  for (int j = 0; j < 6; ++j) v[j] = xb[j * 1024];
  u32* row = (u32*)(featT + ((size_t)b * 1024 + n) * 64);
#pragma unroll
  for (int c2 = 0; c2 < 32; ++c2){
    float y0 = 0.f, y1 = 0.f;
#pragma unroll
    for (int j = 0; j < 6; ++j){
      y0 += wl[(2 * c2) * 6 + j] * v[j];
      y1 += wl[(2 * c2 + 1) * 6 + j] * v[j];
    }
    y0 = fmaxf(scl[2 * c2] * y0 + shl[2 * c2], 0.f);
    y1 = fmaxf(scl[2 * c2 + 1] * y1 + shl[2 * c2 + 1], 0.f);
    row[c2] = (u32)f2bf(y0) | ((u32)f2bf(y1) << 16);
  }
}

// ---------------------------------------------------------------- x_skip pre-act bf16 [b][1024][256]
__global__ __launch_bounds__(256) void kxskip_pre(const u16* __restrict__ featT, const float* __restrict__ w2,
                                                  u16* __restrict__ xpre){
  int b = blockIdx.x >> 4, ot = blockIdx.x & 15, m = threadIdx.x;
  __shared__ float w2s[64][65];
  for (int u = threadIdx.x; u < 64 * 64; u += 256){
    int o = u >> 6, c = u & 63;
    w2s[o][c] = w2[(size_t)(ot * 64 + o) * 64 + c];
  }
  __syncthreads();
  float feat[64];
  const uint4* fr = (const uint4*)(featT + ((size_t)b * 1024 + 4 * m) * 64);
#pragma unroll
  for (int q = 0; q < 8; ++q){
    uint4 pv = fr[q];
    u32 wv[4] = {pv.x, pv.y, pv.z, pv.w};
#pragma unroll
    for (int h = 0; h < 4; ++h){
      feat[q * 8 + 2 * h]     = bf2f((u16)(wv[h] & 0xffff));
      feat[q * 8 + 2 * h + 1] = bf2f((u16)(wv[h] >> 16));
    }
  }
  u16* xb = xpre + ((size_t)b * 1024 + ot * 64) * 256 + m;
  for (int o = 0; o < 64; ++o){
    float acc = 0.f;
#pragma unroll
    for (int c = 0; c < 64; ++c) acc += w2s[o][c] * feat[c];
    xb[(size_t)o * 256] = f2bf(acc);
  }
}

__global__ __launch_bounds__(256) void kxskip_stats(const u16* __restrict__ xpre, const float* __restrict__ g,
                                                    const float* __restrict__ b, float* __restrict__ sc,
                                                    float* __restrict__ sh){
  int o = blockIdx.x, t = threadIdx.x;
  float s = 0.f, ss = 0.f;
  for (int i = t; i < 8192; i += 256){
    int bb = i >> 8, m = i & 255;
    float v = bf2f(xpre[((size_t)bb * 1024 + o) * 256 + m]);
    s += v; ss += v * v;
  }
  __shared__ float rs[256], rq[256];
  rs[t] = s; rq[t] = ss; __syncthreads();
  for (int k = 128; k >= 1; k >>= 1){
    if (t < k){ rs[t] += rs[t + k]; rq[t] += rq[t + k]; }
    __syncthreads();
  }
  if (t == 0){
    float m = rs[0] * (1.f / 8192.f), e2 = rq[0] * (1.f / 8192.f);
    float var = e2 - m * m; if (var < 0.f) var = 0.f;
    float scv = g[o] * rsqrtf(var + BN_EPS);
    sc[o] = scv; sh[o] = b[o] - m * scv;
  }
}

// ---------------------------------------------------------------- FPS: points in LDS, dd in regs, DPP argmax
template<int NPTS, int NSAMP, int PSTRIDE>
__global__ __launch_bounds__(64) void kfps(const float* __restrict__ px_, const float* __restrict__ py_,
                                           const float* __restrict__ pz_, int bstride,
                                           int* __restrict__ fidx, float* __restrict__ nxyz){
  constexpr int PPL = NPTS / 64;
  __shared__ float sx[NPTS], sy[NPTS], sz[NPTS];
  int b = blockIdx.x, lane = threadIdx.x;
  float dd[PPL];
#pragma unroll
  for (int j = 0; j < PPL; ++j){
    int p = j * 64 + lane;
    sx[p] = px_[(size_t)b * bstride + p * PSTRIDE];
    sy[p] = py_[(size_t)b * bstride + p * PSTRIDE];
    sz[p] = pz_[(size_t)b * bstride + p * PSTRIDE];
    dd[j] = 1e10f;
  }
  __syncthreads();
  float cx = sx[0], cy = sy[0], cz = sz[0];
  if (lane == 0){
    fidx[(size_t)b * NSAMP] = 0;
    nxyz[(size_t)b * NSAMP * 3 + 0] = cx;
    nxyz[(size_t)b * NSAMP * 3 + 1] = cy;
    nxyz[(size_t)b * NSAMP * 3 + 2] = cz;
  }
  for (int s = 1; s < NSAMP; ++s){
    float bd = -1.f; u32 bi = 0;
#pragma unroll
    for (int j = 0; j < PPL; ++j){
      int p = j * 64 + lane;
      float dx = __fsub_rn(sx[p], cx);
      float dy = __fsub_rn(sy[p], cy);
      float dz = __fsub_rn(sz[p], cz);
      float d = __fadd_rn(__fadd_rn(__fmul_rn(dx, dx), __fmul_rn(dy, dy)), __fmul_rn(dz, dz));
      float v = fminf(dd[j], d);
      dd[j] = v;
      if (v > bd){ bd = v; bi = (u32)p; }
    }
    u32 win = dpp_arg_reduce<true>(bd, bi);
    cx = sx[win]; cy = sy[win]; cz = sz[win];
    if (lane == 0){
      fidx[(size_t)b * NSAMP + s] = (int)win;
      nxyz[((size_t)b * NSAMP + s) * 3 + 0] = cx;
      nxyz[((size_t)b * NSAMP + s) * 3 + 1] = cy;
      nxyz[((size_t)b * NSAMP + s) * 3 + 2] = cz;
    }
  }
}

// ---------------------------------------------------------------- kNN: DPP argmin, 4 waves/block
template<int NPTS, int SOUT>
__global__ __launch_bounds__(256) void kknn(const float* __restrict__ px_, const float* __restrict__ py_,
                                            const float* __restrict__ pz_, int bstride, int pstride,
                                            const float* __restrict__ cxyz, int* __restrict__ knn){
  constexpr int PPL = NPTS / 64;
  int wid = blockIdx.x * 4 + (threadIdx.x >> 6);
  int lane = threadIdx.x & 63;
  int b = wid / SOUT, s = wid - b * SOUT;
  const float* cb = cxyz + ((size_t)b * SOUT + s) * 3;
  float cx = cb[0], cy = cb[1], cz = cb[2];
  float csq = __fadd_rn(__fadd_rn(__fmul_rn(cx, cx), __fmul_rn(cy, cy)), __fmul_rn(cz, cz));
  float kd[PPL];
#pragma unroll
  for (int j = 0; j < PPL; ++j){
    int p = j * 64 + lane;
    float xx = px_[(size_t)b * bstride + p * pstride];
    float yy = py_[(size_t)b * bstride + p * pstride];
    float zz = pz_[(size_t)b * bstride + p * pstride];
    float psq = __fadd_rn(__fadd_rn(__fmul_rn(xx, xx), __fmul_rn(yy, yy)), __fmul_rn(zz, zz));
    float dot = __fadd_rn(__fadd_rn(__fmul_rn(cx, xx), __fmul_rn(cy, yy)), __fmul_rn(cz, zz));
    kd[j] = __fsub_rn(__fadd_rn(csq, psq), __fmul_rn(2.f, dot));
  }
  int* outp = knn + ((size_t)b * SOUT + s) * 32;
  for (int k = 0; k < 32; ++k){
    float bd = kd[0]; u32 bi = (u32)lane;
#pragma unroll
    for (int j = 1; j < PPL; ++j){
      u32 p = (u32)(j * 64 + lane);
      if (kd[j] < bd){ bd = kd[j]; bi = p; }
    }
    u32 win = dpp_arg_reduce<false>(bd, bi);
    if (lane == 0) outp[k] = (int)win;
#pragma unroll
    for (int j = 0; j < PPL; ++j) if ((u32)(j * 64 + lane) == win) kd[j] = 3e38f;
  }
}

// ---------------------------------------------------------------- pass 0: gather + GEMM1 (MFMA) -> pre1 bf16 + BN1 partials
template<int CIN, int C, int NPTSRC, int SLOG>
__global__ __launch_bounds__(256) void kgm_pre(const u16* __restrict__ featSrc, const int* __restrict__ knnIdx,
                                               const int* __restrict__ fidx, const float* __restrict__ w1f,
                                               const u16* __restrict__ w1bf,
                                               u16* __restrict__ pre1, float* __restrict__ part){
  constexpr int MT  = C / 64;
  constexpr int KS1 = CIN / 32;
  constexpr int P1  = CIN + 8;
  int g = blockIdx.x, t = threadIdx.x, b = g >> SLOG;
  int l = t & 63, wv = t >> 6;
  int lg = l >> 4, ln = l & 15;

  __shared__ int   idxs[32];
  __shared__ float cen[CIN];
  __shared__ float bias[C];
  __shared__ u16   gsT[32][P1];

  if (t < 32) idxs[t] = knnIdx[(size_t)g * 32 + t];
  for (int u = t; u < CIN; u += 256) cen[u] = bf2f(featSrc[((size_t)(b * NPTSRC + fidx[g])) * CIN + u]);
  __syncthreads();

  for (int u = t; u < 32 * CIN / 8; u += 256){
    int k = u & 31, c8 = u >> 5;
    uint4 pv = *(const uint4*)(featSrc + ((size_t)(b * NPTSRC + idxs[k])) * CIN + c8 * 8);
    u32 wvv[4] = {pv.x, pv.y, pv.z, pv.w};
    u32 outw[4];
#pragma unroll
    for (int h = 0; h < 4; ++h){
      float a0 = bf2f((u16)(wvv[h] & 0xffff)) - cen[c8 * 8 + 2 * h];
      float a1 = bf2f((u16)(wvv[h] >> 16))    - cen[c8 * 8 + 2 * h + 1];
      outw[h] = (u32)f2bf(a0) | ((u32)f2bf(a1) << 16);
    }
    *(uint4*)&gsT[k][c8 * 8] = make_uint4(outw[0], outw[1], outw[2], outw[3]);
  }
  if (t < C){
    const float* wr = w1f + (size_t)t * (2 * CIN) + CIN;
    float bs = 0.f;
#pragma unroll 4
    for (int c = 0; c < CIN; ++c) bs += wr[c] * cen[c];
    bias[t] = bs;
  }
  __syncthreads();

  f32x4 acc[MT][2];
#pragma unroll
  for (int mt = 0; mt < MT; ++mt){ acc[mt][0] = (f32x4)0.f; acc[mt][1] = (f32x4)0.f; }
#pragma unroll
  for (int ks = 0; ks < KS1; ++ks){
    int c0 = ks * 32 + lg * 8;
    bf16x8 bfr0 = *(const bf16x8*)&gsT[ln][c0];
    bf16x8 bfr1 = *(const bf16x8*)&gsT[16 + ln][c0];
#pragma unroll
    for (int mt = 0; mt < MT; ++mt){
      int o0 = wv * (C / 4) + mt * 16;
      bf16x8 afr = *(const bf16x8*)(w1bf + (size_t)(o0 + ln) * CIN + c0);
      acc[mt][0] = __builtin_amdgcn_mfma_f32_16x16x32_bf16(afr, bfr0, acc[mt][0], 0, 0, 0);
      acc[mt][1] = __builtin_amdgcn_mfma_f32_16x16x32_bf16(afr, bfr1, acc[mt][1], 0, 0, 0);
    }
  }

  // write pre1[g][o][k] bf16 + per-group stats
#pragma unroll
  for (int mt = 0; mt < MT; ++mt){
    int obase = wv * (C / 4) + mt * 16 + lg * 4;
#pragma unroll
    for (int j = 0; j < 4; ++j){
      int o = obase + j;
      float bv = bias[o];
      float vA = acc[mt][0][j] + bv, vB = acc[mt][1][j] + bv;
      u16* pp = pre1 + ((size_t)g * C + o) * 32 + ln;
      pp[0]  = f2bf(vA);
      pp[16] = f2bf(vB);
      float s = vA + vB, ss = vA * vA + vB * vB;
#pragma unroll
      for (int mk = 1; mk < 16; mk <<= 1){ s += __shfl_xor(s, mk, 64); ss += __shfl_xor(ss, mk, 64); }
      if (ln == 0){
        part[((size_t)g * C + o) * 2 + 0] = s;
        part[((size_t)g * C + o) * 2 + 1] = ss;
      }
    }
  }
}

// ---------------------------------------------------------------- pass 2: pre1 -> BN1+ReLU -> GEMM2 (MFMA) -> partials + pool
template<int C>
__global__ __launch_bounds__(256) void kgm_post(const u16* __restrict__ pre1,
                                                const float* __restrict__ sc1g, const float* __restrict__ sh1g,
                                                const u16* __restrict__ w2bf, const float* __restrict__ gp,
                                                float* __restrict__ part, float* __restrict__ pooledPre){
  constexpr int MT  = C / 64;
  constexpr int KS2 = C / 32;
  constexpr int P2  = C + 8;
  int g = blockIdx.x, t = threadIdx.x;
  int l = t & 63, wv = t >> 6;
  int lg = l >> 4, ln = l & 15;

  __shared__ u16   act2[32][P2];
  __shared__ float sc1s[C], sh1s[C];
  for (int u = t; u < C; u += 256){ sc1s[u] = sc1g[u]; sh1s[u] = sh1g[u]; }
  __syncthreads();

  // coalesced pre1 read (8 bf16/thread/iter), BN1+ReLU, transpose-scatter into act2[k][o]
  for (int u = t; u < C * 4; u += 256){
    uint4 pv = *(const uint4*)(pre1 + (size_t)g * C * 32 + (size_t)u * 8);
    int o = u >> 2, k0 = (u & 3) << 3;
    float s1 = sc1s[o], h1 = sh1s[o];
    u32 wvv[4] = {pv.x, pv.y, pv.z, pv.w};
#pragma unroll
    for (int h = 0; h < 4; ++h){
      float a0 = fmaxf(s1 * bf2f((u16)(wvv[h] & 0xffff)) + h1, 0.f);
      float a1 = fmaxf(s1 * bf2f((u16)(wvv[h] >> 16))    + h1, 0.f);
      act2[k0 + 2 * h][o]     = f2bf(a0);
      act2[k0 + 2 * h + 1][o] = f2bf(a1);
    }
  }
  __syncthreads();

  f32x4 acc[MT][2];
#pragma unroll
  for (int mt = 0; mt < MT; ++mt){ acc[mt][0] = (f32x4)0.f; acc[mt][1] = (f32x4)0.f; }
#pragma unroll
  for (int ks = 0; ks < KS2; ++ks){
    int c0 = ks * 32 + lg * 8;
    bf16x8 bfr0 = *(const bf16x8*)&act2[ln][c0];
    bf16x8 bfr1 = *(const bf16x8*)&act2[16 + ln][c0];
#pragma unroll
    for (int mt = 0; mt < MT; ++mt){
      int o0 = wv * (C / 4) + mt * 16;
      bf16x8 afr = *(const bf16x8*)(w2bf + (size_t)(o0 + ln) * C + c0);
      acc[mt][0] = __builtin_amdgcn_mfma_f32_16x16x32_bf16(afr, bfr0, acc[mt][0], 0, 0, 0);
      acc[mt][1] = __builtin_amdgcn_mfma_f32_16x16x32_bf16(afr, bfr1, acc[mt][1], 0, 0, 0);
    }
  }

#pragma unroll
  for (int mt = 0; mt < MT; ++mt){
    int obase = wv * (C / 4) + mt * 16 + lg * 4;
#pragma unroll
    for (int j = 0; j < 4; ++j){
      float vA = acc[mt][0][j], vB = acc[mt][1][j];
      float s = vA + vB, ss = vA * vA + vB * vB;
      float mx = fmaxf(vA, vB), mn = fminf(vA, vB);
#pragma unroll
      for (int mk = 1; mk < 16; mk <<= 1){
        s += __shfl_xor(s, mk, 64); ss += __shfl_xor(ss, mk, 64);
        mx = fmaxf(mx, __shfl_xor(mx, mk, 64)); mn = fminf(mn, __shfl_xor(mn, mk, 64));
      }
      if (ln == 0){
        int o = obase + j;
        part[((size_t)g * C + o) * 2 + 0] = s;
        part[((size_t)g * C + o) * 2 + 1] = ss;
        pooledPre[(size_t)g * C + o] = (gp[o] >= 0.f) ? mx : mn;
      }
    }
  }
}

// reduce per-group partials -> BN scale/shift (deterministic)
template<int C, int NG>
__global__ __launch_bounds__(256) void kstats_part(const float* __restrict__ part, const float* __restrict__ g_,
                                                   const float* __restrict__ b_, float* __restrict__ sc,
                                                   float* __restrict__ sh){
  int o = blockIdx.x, t = threadIdx.x;
  float s = 0.f, ss = 0.f;
  for (int i = t; i < NG; i += 256){
    s  += part[((size_t)i * C + o) * 2 + 0];
    ss += part[((size_t)i * C + o) * 2 + 1];
  }
  __shared__ float rs[256], rq[256];
  rs[t] = s; rq[t] = ss; __syncthreads();
  for (int k = 128; k >= 1; k >>= 1){
    if (t < k){ rs[t] += rs[t + k]; rq[t] += rq[t + k]; }
    __syncthreads();
  }
  if (t == 0){
    const float inv_n = 1.f / (float)(NG * 32);
    float m = rs[0] * inv_n, e2 = rq[0] * inv_n;
    float var = e2 - m * m; if (var < 0.f) var = 0.f;
    float scv = g_[o] * rsqrtf(var + BN_EPS);
    sc[o] = scv; sh[o] = b_[o] - m * scv;
  }
}

// finalize pooled (stage1): f0feat bf16 [b*512+s][128]
__global__ void kpool_fin1(const float* __restrict__ pooledPre, const float* __restrict__ sc,
                           const float* __restrict__ sh, u16* __restrict__ f0feat){
  int i = blockIdx.x * 256 + threadIdx.x;
  if (i >= 16384 * 128) return;
  int o = i & 127;
  float v = sc[o] * pooledPre[i] + sh[o];
  f0feat[i] = f2bf(fmaxf(v, 0.f));
}

// finalize pooled (stage2): f1T bf16 [b][c][s]
__global__ void kpool_finT(const float* __restrict__ pooledPre, const float* __restrict__ sc,
                           const float* __restrict__ sh, u16* __restrict__ f1T){
  int i = blockIdx.x * 256 + threadIdx.x;
  if (i >= 8192 * 256) return;
  int gg = i >> 8, o = i & 255;
  int b = gg >> 8, s = gg & 255;
  float v = sc[o] * pooledPre[i] + sh[o];
  f1T[((size_t)(b * 256 + o)) * 256 + s] = f2bf(fmaxf(v, 0.f));
}

// ---------------------------------------------------------------- final GEMM: block = (b, 8-o tile), thread = m
__global__ __launch_bounds__(256) void kfinal8(const u16* __restrict__ f1T, const u16* __restrict__ xpre,
                                               const float* __restrict__ scS, const float* __restrict__ shS,
                                               const float* __restrict__ wf, u16* __restrict__ finpre){
  int b = blockIdx.x >> 6, ot = blockIdx.x & 63, m = threadIdx.x;
  int o0 = ot * 8;
  const float* wb = wf + (size_t)o0 * 1280;
  float acc[8];
#pragma unroll
  for (int j = 0; j < 8; ++j) acc[j] = 0.f;
  const u16* fb = f1T + (size_t)b * 256 * 256 + m;
  for (int k = 0; k < 256; ++k){
    float v = bf2f(fb[(size_t)k * 256]);
#pragma unroll
    for (int j = 0; j < 8; ++j) acc[j] = fmaf(wb[(size_t)j * 1280 + k], v, acc[j]);
  }
  const u16* xb = xpre + (size_t)b * 1024 * 256 + m;
  for (int k = 0; k < 1024; ++k){
    float xv = bf2f(xb[(size_t)k * 256]);
    float v = fmaxf(scS[k] * xv + shS[k], 0.f);
#pragma unroll
    for (int j = 0; j < 8; ++j) acc[j] = fmaf(wb[(size_t)j * 1280 + 256 + k], v, acc[j]);
  }
#pragma unroll
  for (int j = 0; j < 8; ++j)
    finpre[((size_t)b * 512 + o0 + j) * 256 + m] = f2bf(acc[j]);
}

__global__ __launch_bounds__(256) void kstats_fin(const u16* __restrict__ finpre, const float* __restrict__ g,
                                                  const float* __restrict__ b, float* __restrict__ sc,
                                                  float* __restrict__ sh){
  int o = blockIdx.x, t = threadIdx.x;
  float s = 0.f, ss = 0.f;
  for (int i = t; i < 8192; i += 256){
    int bb = i >> 8, m = i & 255;
    float v = bf2f(finpre[((size_t)bb * 512 + o) * 256 + m]);
    s += v; ss += v * v;
  }
  __shared__ float rs[256], rq[256];
  rs[t] = s; rq[t] = ss; __syncthreads();
  for (int k = 128; k >= 1; k >>= 1){
    if (t < k){ rs[t] += rs[t + k]; rq[t] += rq[t + k]; }
    __syncthreads();
  }
  if (t == 0){
    float m = rs[0] * (1.f / 8192.f), e2 = rq[0] * (1.f / 8192.f);
    float var = e2 - m * m; if (var < 0.f) var = 0.f;
    float scv = g[o] * rsqrtf(var + BN_EPS);
    sc[o] = scv; sh[o] = b[o] - m * scv;
  }
}

__global__ void kapply(const u16* __restrict__ finpre, const float* __restrict__ sc,
                       const float* __restrict__ sh, float* __restrict__ out){
  int i = blockIdx.x * 256 + threadIdx.x;
  if (i >= 32 * 512 * 256) return;
  int o = (i >> 8) & 511;
  float v = sc[o] * bf2f(finpre[i]) + sh[o];
  out[i] = v > 0.f ? v : 0.2f * v;
}

// ================================================================ host
extern "C" void kernel_launch(void* const* d_in, const int* in_sizes, int n_in,
                              void* d_out, int out_size, void* d_ws, size_t ws_size,
                              hipStream_t stream){
  const float* x    = (const float*)d_in[0];
  const float* w_c1 = (const float*)d_in[1];
  const float* g1   = (const float*)d_in[2];
  const float* b1   = (const float*)d_in[3];
  const float* w_c2 = (const float*)d_in[4];
  const float* g2   = (const float*)d_in[5];
  const float* b2   = (const float*)d_in[6];
  const float* l0w1 = (const float*)d_in[7];
  const float* l0g1 = (const float*)d_in[8];
  const float* l0b1 = (const float*)d_in[9];
  const float* l0w2 = (const float*)d_in[10];
  const float* l0g2 = (const float*)d_in[11];
  const float* l0b2 = (const float*)d_in[12];
  const float* l1w1 = (const float*)d_in[13];
  const float* l1g1 = (const float*)d_in[14];
  const float* l1b1 = (const float*)d_in[15];
  const float* l1w2 = (const float*)d_in[16];
  const float* l1g2 = (const float*)d_in[17];
  const float* l1b2 = (const float*)d_in[18];
  const float* wf   = (const float*)d_in[19];
  const float* gf   = (const float*)d_in[20];
  const float* bfp  = (const float*)d_in[21];
  float* out = (float*)d_out;

  char* ws = (char*)d_ws;
  size_t cur = 0;
  auto alloc = [&](size_t bytes) -> char* {
    char* p = ws + cur;
    cur += (bytes + 255) & ~(size_t)255;
    return p;
  };
  float* sc1  = (float*)alloc(64 * 4);    float* sh1  = (float*)alloc(64 * 4);
  float* scSK = (float*)alloc(1024 * 4);  float* shSK = (float*)alloc(1024 * 4);
  float* scA1 = (float*)alloc(128 * 4);   float* shA1 = (float*)alloc(128 * 4);
  float* scA2 = (float*)alloc(128 * 4);   float* shA2 = (float*)alloc(128 * 4);
  float* scC1 = (float*)alloc(256 * 4);   float* shC1 = (float*)alloc(256 * 4);
  float* scC2 = (float*)alloc(256 * 4);   float* shC2 = (float*)alloc(256 * 4);
  float* scF  = (float*)alloc(512 * 4);   float* shF  = (float*)alloc(512 * 4);
  u16* w1bf1 = (u16*)alloc((size_t)128 * 64 * 2);
  u16* w2bf1 = (u16*)alloc((size_t)128 * 128 * 2);
  u16* w1bf2 = (u16*)alloc((size_t)256 * 128 * 2);
  u16* w2bf2 = (u16*)alloc((size_t)256 * 256 * 2);
  u16*   featT  = (u16*)  alloc((size_t)32 * 1024 * 64 * 2);
  u16*   xpre   = (u16*)  alloc((size_t)32 * 1024 * 256 * 2);
  int*   fidx1  = (int*)  alloc((size_t)32 * 512 * 4);
  float* nxyz1  = (float*)alloc((size_t)32 * 512 * 3 * 4);
  int*   knn1   = (int*)  alloc((size_t)32 * 512 * 32 * 4);
  int*   fidx2  = (int*)  alloc((size_t)32 * 256 * 4);
  float* nxyz2  = (float*)alloc((size_t)32 * 256 * 3 * 4);
  int*   knn2   = (int*)  alloc((size_t)32 * 256 * 32 * 4);
  u16*   pre1   = (u16*)  alloc((size_t)16384 * 128 * 32 * 2);  // == 8192*256*32, reused by stage 2
  float* part   = (float*)alloc((size_t)16384 * 128 * 2 * 4);   // == 8192*256*2, reused by stage 2
  float* pooledPre = (float*)alloc((size_t)16384 * 128 * 4);    // == 8192*256, reused by stage 2
  u16*   f0feat = (u16*)  alloc((size_t)16384 * 128 * 2);
  u16*   f1T    = (u16*)  alloc((size_t)32 * 256 * 256 * 2);
  u16*   finpre = (u16*)  alloc((size_t)32 * 512 * 256 * 2);

  if (cur > ws_size){
    float code = -1000.f - (float)(ws_size >> 20);
    kfb<<<(out_size + 255) / 256, 256, 0, stream>>>(out, out_size, code);
    return;
  }

  // bf16 weight casts (left half of w1; full w2)
  kcast_bf<<<(128 * 64 + 255) / 256, 256, 0, stream>>>(l0w1, 128, 64, 128, 0, w1bf1);
  kcast_bf<<<(128 * 128 + 255) / 256, 256, 0, stream>>>(l0w2, 128, 128, 128, 0, w2bf1);
  kcast_bf<<<(256 * 128 + 255) / 256, 256, 0, stream>>>(l1w1, 256, 128, 256, 0, w1bf2);
  kcast_bf<<<(256 * 256 + 255) / 256, 256, 0, stream>>>(l1w2, 256, 256, 256, 0, w2bf2);

  // stage A
  kA_stats<<<64, 256, 0, stream>>>(x, w_c1, g1, b1, sc1, sh1);
  kA_feat<<<128, 256, 0, stream>>>(x, w_c1, sc1, sh1, featT);

  // x_skip
  kxskip_pre<<<512, 256, 0, stream>>>(featT, w_c2, xpre);
  kxskip_stats<<<1024, 256, 0, stream>>>(xpre, g2, b2, scSK, shSK);

  // stage 1 selections
  kfps<1024, 512, 1><<<32, 64, 0, stream>>>(x, x + 1024, x + 2048, 6144, fidx1, nxyz1);
  kknn<1024, 512><<<32 * 512 / 4, 256, 0, stream>>>(x, x + 1024, x + 2048, 6144, 1, nxyz1, knn1);

  // stage 1 local_op (pre -> stats -> post)
  kgm_pre<64, 128, 1024, 9><<<16384, 256, 0, stream>>>(featT, knn1, fidx1, l0w1, w1bf1, pre1, part);
  kstats_part<128, 16384><<<128, 256, 0, stream>>>(part, l0g1, l0b1, scA1, shA1);
  kgm_post<128><<<16384, 256, 0, stream>>>(pre1, scA1, shA1, w2bf1, l0g2, part, pooledPre);
  kstats_part<128, 16384><<<128, 256, 0, stream>>>(part, l0g2, l0b2, scA2, shA2);
  kpool_fin1<<<8192, 256, 0, stream>>>(pooledPre, scA2, shA2, f0feat);

  // stage 2 selections
  kfps<512, 256, 3><<<32, 64, 0, stream>>>(nxyz1, nxyz1 + 1, nxyz1 + 2, 1536, fidx2, nxyz2);
  kknn<512, 256><<<32 * 256 / 4, 256, 0, stream>>>(nxyz1, nxyz1 + 1, nxyz1 + 2, 1536, 3, nxyz2, knn2);

  // stage 2 local_op
  kgm_pre<128, 256, 512, 8><<<8192, 256, 0, stream>>>(f0feat, knn2, fidx2, l1w1, w1bf2, pre1, part);
  kstats_part<256, 8192><<<256, 256, 0, stream>>>(part, l1g1, l1b1, scC1, shC1);
  kgm_post<256><<<8192, 256, 0, stream>>>(pre1, scC1, shC1, w2bf2, l1g2, part, pooledPre);
  kstats_part<256, 8192><<<256, 256, 0, stream>>>(part, l1g2, l1b2, scC2, shC2);
  kpool_finT<<<8192, 256, 0, stream>>>(pooledPre, scC2, shC2, f1T);

  // final
  kfinal8<<<2048, 256, 0, stream>>>(f1T, xpre, scSK, shSK, wf, finpre);
  kstats_fin<<<512, 256, 0, stream>>>(finpre, gf, bfp, scF, shF);
  kapply<<<16384, 256, 0, stream>>>(finpre, scF, shF, out);
}

// Round 16
// 1810.043 us; speedup vs baseline: 2.0052x; 1.0043x over previous
//
#include <hip/hip_runtime.h>
#include <stdint.h>

typedef unsigned int u32;
typedef unsigned short u16;
typedef __attribute__((ext_vector_type(8))) short bf16x8;   // 8 bf16 = 4 VGPRs
typedef __attribute__((ext_vector_type(4))) float f32x4;

#define DEV __device__ __forceinline__
#define BN_EPS 1e-5f

DEV float bf2f(u16 u){ return __uint_as_float(((u32)u) << 16); }
DEV u16 f2bf(float f){ u32 x = __float_as_uint(f); return (u16)((x + 0x7FFFu + ((x >> 16) & 1u)) >> 16); }

// ---------------------------------------------------------------- DPP wave64 argmax/argmin reduce
template<int CTRL, int RMASK, bool MAXOP>
DEV void dpp_step(float& d, u32& i){
  int ds = __float_as_int(d);
  int is = (int)i;
  int dn_ = __builtin_amdgcn_update_dpp(ds, ds, CTRL, RMASK, 0xf, false);
  int in_ = __builtin_amdgcn_update_dpp(is, is, CTRL, RMASK, 0xf, false);
  float dn = __int_as_float(dn_);
  u32 ii = (u32)in_;
  bool take = MAXOP ? (dn > d || (dn == d && ii < i))
                    : (dn < d || (dn == d && ii < i));
  if (take){ d = dn; i = ii; }
}

template<bool MAXOP>
DEV u32 dpp_arg_reduce(float& d, u32& i){
  dpp_step<0x111, 0xf, MAXOP>(d, i);
  dpp_step<0x112, 0xf, MAXOP>(d, i);
  dpp_step<0x114, 0xf, MAXOP>(d, i);
  dpp_step<0x118, 0xf, MAXOP>(d, i);
  dpp_step<0x142, 0xa, MAXOP>(d, i);
  dpp_step<0x143, 0xc, MAXOP>(d, i);
  return (u32)__builtin_amdgcn_readlane((int)i, 63);
}

// ---------------------------------------------------------------- ws-too-small fallback
__global__ void kfb(float* out, int n, float code){
  int i = blockIdx.x * 256 + threadIdx.x;
  if (i < n) out[i] = (i == 0) ? code : 0.f;
}

// cast weights to bf16
__global__ void kcast_bf(const float* __restrict__ src, int rows, int cols, int srcStride, int colOff,
                         u16* __restrict__ dst){
  int i = blockIdx.x * 256 + threadIdx.x;
  if (i >= rows * cols) return;
  int r = i / cols, c = i - r * cols;
  dst[r * cols + c] = f2bf(src[r * srcStride + colOff + c]);
}

// ---------------------------------------------------------------- stage A: BN1 stats (deterministic)
__global__ __launch_bounds__(256) void kA_stats(const float* __restrict__ x, const float* __restrict__ w,
                                                const float* __restrict__ g, const float* __restrict__ b,
                                                float* __restrict__ sc, float* __restrict__ sh){
  int c = blockIdx.x, t = threadIdx.x;
  float wr[6];
#pragma unroll
  for (int j = 0; j < 6; ++j) wr[j] = w[c * 6 + j];
  float s = 0.f, ss = 0.f;
  for (int i = t; i < 32768; i += 256){
    int bb = i >> 10, n = i & 1023;
    const float* xb = x + bb * 6144 + n;
    float y = 0.f;
#pragma unroll
    for (int j = 0; j < 6; ++j) y += wr[j] * xb[j * 1024];
    s += y; ss += y * y;
  }
  __shared__ float rs[256], rq[256];
  rs[t] = s; rq[t] = ss; __syncthreads();
  for (int k = 128; k >= 1; k >>= 1){
    if (t < k){ rs[t] += rs[t + k]; rq[t] += rq[t + k]; }
    __syncthreads();
  }
  if (t == 0){
    float m = rs[0] * (1.f / 32768.f), e2 = rq[0] * (1.f / 32768.f);
    float var = e2 - m * m; if (var < 0.f) var = 0.f;
    float scv = g[c] * rsqrtf(var + BN_EPS);
    sc[c] = scv; sh[c] = b[c] - m * scv;
  }
}

// stage A apply -> featT bf16 [b][n][64]
__global__ __launch_bounds__(256) void kA_feat(const float* __restrict__ x, const float* __restrict__ w,
                                               const float* __restrict__ sc, const float* __restrict__ sh,
                                               u16* __restrict__ featT){
  int b = blockIdx.x >> 2, t = threadIdx.x;
  int n = ((blockIdx.x & 3) << 8) + t;
  __shared__ float wl[384], scl[64], shl[64];
  for (int u = t; u < 384; u += 256) wl[u] = w[u];
  if (t < 64){ scl[t] = sc[t]; shl[t] = sh[t]; }
  __syncthreads();
  float v[6];
  const float* xb = x + b * 6144 + n;
#pragma unroll
  for (int j = 0; j < 6; ++j) v[j] = xb[j * 1024];
  u32* row = (u32*)(featT + ((size_t)b * 1024 + n) * 64);
#pragma unroll
  for (int c2 = 0; c2 < 32; ++c2){
    float y0 = 0.f, y1 = 0.f;
#pragma unroll
    for (int j = 0; j < 6; ++j){
      y0 += wl[(2 * c2) * 6 + j] * v[j];
      y1 += wl[(2 * c2 + 1) * 6 + j] * v[j];
    }
    y0 = fmaxf(scl[2 * c2] * y0 + shl[2 * c2], 0.f);
    y1 = fmaxf(scl[2 * c2 + 1] * y1 + shl[2 * c2 + 1], 0.f);
    row[c2] = (u32)f2bf(y0) | ((u32)f2bf(y1) << 16);
  }
}

// ---------------------------------------------------------------- x_skip pre-act bf16 [b][1024][256]
__global__ __launch_bounds__(256) void kxskip_pre(const u16* __restrict__ featT, const float* __restrict__ w2,
                                                  u16* __restrict__ xpre){
  int b = blockIdx.x >> 4, ot = blockIdx.x & 15, m = threadIdx.x;
  __shared__ float w2s[64][65];
  for (int u = threadIdx.x; u < 64 * 64; u += 256){
    int o = u >> 6, c = u & 63;
    w2s[o][c] = w2[(size_t)(ot * 64 + o) * 64 + c];
  }
  __syncthreads();
  float feat[64];
  const uint4* fr = (const uint4*)(featT + ((size_t)b * 1024 + 4 * m) * 64);
#pragma unroll
  for (int q = 0; q < 8; ++q){
    uint4 pv = fr[q];
    u32 wv[4] = {pv.x, pv.y, pv.z, pv.w};
#pragma unroll
    for (int h = 0; h < 4; ++h){
      feat[q * 8 + 2 * h]     = bf2f((u16)(wv[h] & 0xffff));
      feat[q * 8 + 2 * h + 1] = bf2f((u16)(wv[h] >> 16));
    }
  }
  u16* xb = xpre + ((size_t)b * 1024 + ot * 64) * 256 + m;
  for (int o = 0; o < 64; ++o){
    float acc = 0.f;
#pragma unroll
    for (int c = 0; c < 64; ++c) acc += w2s[o][c] * feat[c];
    xb[(size_t)o * 256] = f2bf(acc);
  }
}

__global__ __launch_bounds__(256) void kxskip_stats(const u16* __restrict__ xpre, const float* __restrict__ g,
                                                    const float* __restrict__ b, float* __restrict__ sc,
                                                    float* __restrict__ sh){
  int o = blockIdx.x, t = threadIdx.x;
  float s = 0.f, ss = 0.f;
  for (int i = t; i < 8192; i += 256){
    int bb = i >> 8, m = i & 255;
    float v = bf2f(xpre[((size_t)bb * 1024 + o) * 256 + m]);
    s += v; ss += v * v;
  }
  __shared__ float rs[256], rq[256];
  rs[t] = s; rq[t] = ss; __syncthreads();
  for (int k = 128; k >= 1; k >>= 1){
    if (t < k){ rs[t] += rs[t + k]; rq[t] += rq[t + k]; }
    __syncthreads();
  }
  if (t == 0){
    float m = rs[0] * (1.f / 8192.f), e2 = rq[0] * (1.f / 8192.f);
    float var = e2 - m * m; if (var < 0.f) var = 0.f;
    float scv = g[o] * rsqrtf(var + BN_EPS);
    sc[o] = scv; sh[o] = b[o] - m * scv;
  }
}

// ---------------------------------------------------------------- FPS: coords in REGISTERS (dist) + LDS (winner bcast)
// No pointer escape of the register arrays (unrolled compile-time indices only) -> stays in VGPRs.
// __launch_bounds__(64,1): grid = 32 blocks; occupancy irrelevant, allow full VGPR budget.
template<int NPTS, int NSAMP, int PSTRIDE>
__global__ __launch_bounds__(64, 1) void kfps(const float* __restrict__ px_, const float* __restrict__ py_,
                                              const float* __restrict__ pz_, int bstride,
                                              int* __restrict__ fidx, float* __restrict__ nxyz){
  constexpr int PPL = NPTS / 64;
  __shared__ float sx[NPTS], sy[NPTS], sz[NPTS];
  int b = blockIdx.x, lane = threadIdx.x;
  float rx[PPL], ry[PPL], rz[PPL], dd[PPL];
#pragma unroll
  for (int j = 0; j < PPL; ++j){
    int p = j * 64 + lane;
    float vx = px_[(size_t)b * bstride + p * PSTRIDE];
    float vy = py_[(size_t)b * bstride + p * PSTRIDE];
    float vz = pz_[(size_t)b * bstride + p * PSTRIDE];
    rx[j] = vx; ry[j] = vy; rz[j] = vz;
    sx[p] = vx; sy[p] = vy; sz[p] = vz;
    dd[j] = 1e10f;
  }
  __syncthreads();
  float cx = sx[0], cy = sy[0], cz = sz[0];
  if (lane == 0){
    fidx[(size_t)b * NSAMP] = 0;
    nxyz[(size_t)b * NSAMP * 3 + 0] = cx;
    nxyz[(size_t)b * NSAMP * 3 + 1] = cy;
    nxyz[(size_t)b * NSAMP * 3 + 2] = cz;
  }
  for (int s = 1; s < NSAMP; ++s){
    float bd = -1.f; u32 bi = 0;
#pragma unroll
    for (int j = 0; j < PPL; ++j){
      float dx = __fsub_rn(rx[j], cx);
      float dy = __fsub_rn(ry[j], cy);
      float dz = __fsub_rn(rz[j], cz);
      float d = __fadd_rn(__fadd_rn(__fmul_rn(dx, dx), __fmul_rn(dy, dy)), __fmul_rn(dz, dz));
      float v = fminf(dd[j], d);
      dd[j] = v;
      if (v > bd){ bd = v; bi = (u32)(j * 64 + lane); }  // strict > keeps lowest j (np.argmax)
    }
    u32 win = dpp_arg_reduce<true>(bd, bi);
    cx = sx[win]; cy = sy[win]; cz = sz[win];   // uniform LDS broadcast (only LDS use per iter)
    if (lane == 0){
      fidx[(size_t)b * NSAMP + s] = (int)win;
      nxyz[((size_t)b * NSAMP + s) * 3 + 0] = cx;
      nxyz[((size_t)b * NSAMP + s) * 3 + 1] = cy;
      nxyz[((size_t)b * NSAMP + s) * 3 + 2] = cz;
    }
  }
}

// ---------------------------------------------------------------- kNN: DPP argmin, 4 waves/block
template<int NPTS, int SOUT>
__global__ __launch_bounds__(256) void kknn(const float* __restrict__ px_, const float* __restrict__ py_,
                                            const float* __restrict__ pz_, int bstride, int pstride,
                                            const float* __restrict__ cxyz, int* __restrict__ knn){
  constexpr int PPL = NPTS / 64;
  int wid = blockIdx.x * 4 + (threadIdx.x >> 6);
  int lane = threadIdx.x & 63;
  int b = wid / SOUT, s = wid - b * SOUT;
  const float* cb = cxyz + ((size_t)b * SOUT + s) * 3;
  float cx = cb[0], cy = cb[1], cz = cb[2];
  float csq = __fadd_rn(__fadd_rn(__fmul_rn(cx, cx), __fmul_rn(cy, cy)), __fmul_rn(cz, cz));
  float kd[PPL];
#pragma unroll
  for (int j = 0; j < PPL; ++j){
    int p = j * 64 + lane;
    float xx = px_[(size_t)b * bstride + p * pstride];
    float yy = py_[(size_t)b * bstride + p * pstride];
    float zz = pz_[(size_t)b * bstride + p * pstride];
    float psq = __fadd_rn(__fadd_rn(__fmul_rn(xx, xx), __fmul_rn(yy, yy)), __fmul_rn(zz, zz));
    float dot = __fadd_rn(__fadd_rn(__fmul_rn(cx, xx), __fmul_rn(cy, yy)), __fmul_rn(cz, zz));
    kd[j] = __fsub_rn(__fadd_rn(csq, psq), __fmul_rn(2.f, dot));
  }
  int* outp = knn + ((size_t)b * SOUT + s) * 32;
  for (int k = 0; k < 32; ++k){
    float bd = kd[0]; u32 bi = (u32)lane;
#pragma unroll
    for (int j = 1; j < PPL; ++j){
      u32 p = (u32)(j * 64 + lane);
      if (kd[j] < bd){ bd = kd[j]; bi = p; }
    }
    u32 win = dpp_arg_reduce<false>(bd, bi);
    if (lane == 0) outp[k] = (int)win;
#pragma unroll
    for (int j = 0; j < PPL; ++j) if ((u32)(j * 64 + lane) == win) kd[j] = 3e38f;
  }
}

// ---------------------------------------------------------------- pass 0: gather + GEMM1 (MFMA) -> pre1 bf16 + BN1 partials
template<int CIN, int C, int NPTSRC, int SLOG>
__global__ __launch_bounds__(256) void kgm_pre(const u16* __restrict__ featSrc, const int* __restrict__ knnIdx,
                                               const int* __restrict__ fidx, const float* __restrict__ w1f,
                                               const u16* __restrict__ w1bf,
                                               u16* __restrict__ pre1, float* __restrict__ part){
  constexpr int MT  = C / 64;
  constexpr int KS1 = CIN / 32;
  constexpr int P1  = CIN + 8;
  int g = blockIdx.x, t = threadIdx.x, b = g >> SLOG;
  int l = t & 63, wv = t >> 6;
  int lg = l >> 4, ln = l & 15;

  __shared__ int   idxs[32];
  __shared__ float cen[CIN];
  __shared__ float bias[C];
  __shared__ u16   gsT[32][P1];

  if (t < 32) idxs[t] = knnIdx[(size_t)g * 32 + t];
  for (int u = t; u < CIN; u += 256) cen[u] = bf2f(featSrc[((size_t)(b * NPTSRC + fidx[g])) * CIN + u]);
  __syncthreads();

  for (int u = t; u < 32 * CIN / 8; u += 256){
    int k = u & 31, c8 = u >> 5;
    uint4 pv = *(const uint4*)(featSrc + ((size_t)(b * NPTSRC + idxs[k])) * CIN + c8 * 8);
    u32 wvv[4] = {pv.x, pv.y, pv.z, pv.w};
    u32 outw[4];
#pragma unroll
    for (int h = 0; h < 4; ++h){
      float a0 = bf2f((u16)(wvv[h] & 0xffff)) - cen[c8 * 8 + 2 * h];
      float a1 = bf2f((u16)(wvv[h] >> 16))    - cen[c8 * 8 + 2 * h + 1];
      outw[h] = (u32)f2bf(a0) | ((u32)f2bf(a1) << 16);
    }
    *(uint4*)&gsT[k][c8 * 8] = make_uint4(outw[0], outw[1], outw[2], outw[3]);
  }
  if (t < C){
    const float* wr = w1f + (size_t)t * (2 * CIN) + CIN;
    float bs = 0.f;
#pragma unroll 4
    for (int c = 0; c < CIN; ++c) bs += wr[c] * cen[c];
    bias[t] = bs;
  }
  __syncthreads();

  f32x4 acc[MT][2];
#pragma unroll
  for (int mt = 0; mt < MT; ++mt){ acc[mt][0] = (f32x4)0.f; acc[mt][1] = (f32x4)0.f; }
#pragma unroll
  for (int ks = 0; ks < KS1; ++ks){
    int c0 = ks * 32 + lg * 8;
    bf16x8 bfr0 = *(const bf16x8*)&gsT[ln][c0];
    bf16x8 bfr1 = *(const bf16x8*)&gsT[16 + ln][c0];
#pragma unroll
    for (int mt = 0; mt < MT; ++mt){
      int o0 = wv * (C / 4) + mt * 16;
      bf16x8 afr = *(const bf16x8*)(w1bf + (size_t)(o0 + ln) * CIN + c0);
      acc[mt][0] = __builtin_amdgcn_mfma_f32_16x16x32_bf16(afr, bfr0, acc[mt][0], 0, 0, 0);
      acc[mt][1] = __builtin_amdgcn_mfma_f32_16x16x32_bf16(afr, bfr1, acc[mt][1], 0, 0, 0);
    }
  }

#pragma unroll
  for (int mt = 0; mt < MT; ++mt){
    int obase = wv * (C / 4) + mt * 16 + lg * 4;
#pragma unroll
    for (int j = 0; j < 4; ++j){
      int o = obase + j;
      float bv = bias[o];
      float vA = acc[mt][0][j] + bv, vB = acc[mt][1][j] + bv;
      u16* pp = pre1 + ((size_t)g * C + o) * 32 + ln;
      pp[0]  = f2bf(vA);
      pp[16] = f2bf(vB);
      float s = vA + vB, ss = vA * vA + vB * vB;
#pragma unroll
      for (int mk = 1; mk < 16; mk <<= 1){ s += __shfl_xor(s, mk, 64); ss += __shfl_xor(ss, mk, 64); }
      if (ln == 0){
        part[((size_t)g * C + o) * 2 + 0] = s;
        part[((size_t)g * C + o) * 2 + 1] = ss;
      }
    }
  }
}

// ---------------------------------------------------------------- pass 2: pre1 -> BN1+ReLU -> GEMM2 (MFMA) -> partials + pool
template<int C>
__global__ __launch_bounds__(256) void kgm_post(const u16* __restrict__ pre1,
                                                const float* __restrict__ sc1g, const float* __restrict__ sh1g,
                                                const u16* __restrict__ w2bf, const float* __restrict__ gp,
                                                float* __restrict__ part, float* __restrict__ pooledPre){
  constexpr int MT  = C / 64;
  constexpr int KS2 = C / 32;
  constexpr int P2  = C + 8;
  int g = blockIdx.x, t = threadIdx.x;
  int l = t & 63, wv = t >> 6;
  int lg = l >> 4, ln = l & 15;

  __shared__ u16   act2[32][P2];
  __shared__ float sc1s[C], sh1s[C];
  for (int u = t; u < C; u += 256){ sc1s[u] = sc1g[u]; sh1s[u] = sh1g[u]; }
  __syncthreads();

  for (int u = t; u < C * 4; u += 256){
    uint4 pv = *(const uint4*)(pre1 + (size_t)g * C * 32 + (size_t)u * 8);
    int o = u >> 2, k0 = (u & 3) << 3;
    float s1 = sc1s[o], h1 = sh1s[o];
    u32 wvv[4] = {pv.x, pv.y, pv.z, pv.w};
#pragma unroll
    for (int h = 0; h < 4; ++h){
      float a0 = fmaxf(s1 * bf2f((u16)(wvv[h] & 0xffff)) + h1, 0.f);
      float a1 = fmaxf(s1 * bf2f((u16)(wvv[h] >> 16))    + h1, 0.f);
      act2[k0 + 2 * h][o]     = f2bf(a0);
      act2[k0 + 2 * h + 1][o] = f2bf(a1);
    }
  }
  __syncthreads();

  f32x4 acc[MT][2];
#pragma unroll
  for (int mt = 0; mt < MT; ++mt){ acc[mt][0] = (f32x4)0.f; acc[mt][1] = (f32x4)0.f; }
#pragma unroll
  for (int ks = 0; ks < KS2; ++ks){
    int c0 = ks * 32 + lg * 8;
    bf16x8 bfr0 = *(const bf16x8*)&act2[ln][c0];
    bf16x8 bfr1 = *(const bf16x8*)&act2[16 + ln][c0];
#pragma unroll
    for (int mt = 0; mt < MT; ++mt){
      int o0 = wv * (C / 4) + mt * 16;
      bf16x8 afr = *(const bf16x8*)(w2bf + (size_t)(o0 + ln) * C + c0);
      acc[mt][0] = __builtin_amdgcn_mfma_f32_16x16x32_bf16(afr, bfr0, acc[mt][0], 0, 0, 0);
      acc[mt][1] = __builtin_amdgcn_mfma_f32_16x16x32_bf16(afr, bfr1, acc[mt][1], 0, 0, 0);
    }
  }

#pragma unroll
  for (int mt = 0; mt < MT; ++mt){
    int obase = wv * (C / 4) + mt * 16 + lg * 4;
#pragma unroll
    for (int j = 0; j < 4; ++j){
      float vA = acc[mt][0][j], vB = acc[mt][1][j];
      float s = vA + vB, ss = vA * vA + vB * vB;
      float mx = fmaxf(vA, vB), mn = fminf(vA, vB);
#pragma unroll
      for (int mk = 1; mk < 16; mk <<= 1){
        s += __shfl_xor(s, mk, 64); ss += __shfl_xor(ss, mk, 64);
        mx = fmaxf(mx, __shfl_xor(mx, mk, 64)); mn = fminf(mn, __shfl_xor(mn, mk, 64));
      }
      if (ln == 0){
        int o = obase + j;
        part[((size_t)g * C + o) * 2 + 0] = s;
        part[((size_t)g * C + o) * 2 + 1] = ss;
        pooledPre[(size_t)g * C + o] = (gp[o] >= 0.f) ? mx : mn;
      }
    }
  }
}

// reduce per-group partials -> BN scale/shift (deterministic)
template<int C, int NG>
__global__ __launch_bounds__(256) void kstats_part(const float* __restrict__ part, const float* __restrict__ g_,
                                                   const float* __restrict__ b_, float* __restrict__ sc,
                                                   float* __restrict__ sh){
  int o = blockIdx.x, t = threadIdx.x;
  float s = 0.f, ss = 0.f;
  for (int i = t; i < NG; i += 256){
    s  += part[((size_t)i * C + o) * 2 + 0];
    ss += part[((size_t)i * C + o) * 2 + 1];
  }
  __shared__ float rs[256], rq[256];
  rs[t] = s; rq[t] = ss; __syncthreads();
  for (int k = 128; k >= 1; k >>= 1){
    if (t < k){ rs[t] += rs[t + k]; rq[t] += rq[t + k]; }
    __syncthreads();
  }
  if (t == 0){
    const float inv_n = 1.f / (float)(NG * 32);
    float m = rs[0] * inv_n, e2 = rq[0] * inv_n;
    float var = e2 - m * m; if (var < 0.f) var = 0.f;
    float scv = g_[o] * rsqrtf(var + BN_EPS);
    sc[o] = scv; sh[o] = b_[o] - m * scv;
  }
}

// finalize pooled (stage1): f0feat bf16 [b*512+s][128]
__global__ void kpool_fin1(const float* __restrict__ pooledPre, const float* __restrict__ sc,
                           const float* __restrict__ sh, u16* __restrict__ f0feat){
  int i = blockIdx.x * 256 + threadIdx.x;
  if (i >= 16384 * 128) return;
  int o = i & 127;
  float v = sc[o] * pooledPre[i] + sh[o];
  f0feat[i] = f2bf(fmaxf(v, 0.f));
}

// finalize pooled (stage2): f1T bf16 [b][c][s]
__global__ void kpool_finT(const float* __restrict__ pooledPre, const float* __restrict__ sc,
                           const float* __restrict__ sh, u16* __restrict__ f1T){
  int i = blockIdx.x * 256 + threadIdx.x;
  if (i >= 8192 * 256) return;
  int gg = i >> 8, o = i & 255;
  int b = gg >> 8, s = gg & 255;
  float v = sc[o] * pooledPre[i] + sh[o];
  f1T[((size_t)(b * 256 + o)) * 256 + s] = f2bf(fmaxf(v, 0.f));
}

// ---------------------------------------------------------------- final GEMM: block = (b, 8-o tile), thread = m
__global__ __launch_bounds__(256) void kfinal8(const u16* __restrict__ f1T, const u16* __restrict__ xpre,
                                               const float* __restrict__ scS, const float* __restrict__ shS,
                                               const float* __restrict__ wf, u16* __restrict__ finpre){
  int b = blockIdx.x >> 6, ot = blockIdx.x & 63, m = threadIdx.x;
  int o0 = ot * 8;
  const float* wb = wf + (size_t)o0 * 1280;
  float acc[8];
#pragma unroll
  for (int j = 0; j < 8; ++j) acc[j] = 0.f;
  const u16* fb = f1T + (size_t)b * 256 * 256 + m;
  for (int k = 0; k < 256; ++k){
    float v = bf2f(fb[(size_t)k * 256]);
#pragma unroll
    for (int j = 0; j < 8; ++j) acc[j] = fmaf(wb[(size_t)j * 1280 + k], v, acc[j]);
  }
  const u16* xb = xpre + (size_t)b * 1024 * 256 + m;
  for (int k = 0; k < 1024; ++k){
    float xv = bf2f(xb[(size_t)k * 256]);
    float v = fmaxf(scS[k] * xv + shS[k], 0.f);
#pragma unroll
    for (int j = 0; j < 8; ++j) acc[j] = fmaf(wb[(size_t)j * 1280 + 256 + k], v, acc[j]);
  }
#pragma unroll
  for (int j = 0; j < 8; ++j)
    finpre[((size_t)b * 512 + o0 + j) * 256 + m] = f2bf(acc[j]);
}

__global__ __launch_bounds__(256) void kstats_fin(const u16* __restrict__ finpre, const float* __restrict__ g,
                                                  const float* __restrict__ b, float* __restrict__ sc,
                                                  float* __restrict__ sh){
  int o = blockIdx.x, t = threadIdx.x;
  float s = 0.f, ss = 0.f;
  for (int i = t; i < 8192; i += 256){
    int bb = i >> 8, m = i & 255;
    float v = bf2f(finpre[((size_t)bb * 512 + o) * 256 + m]);
    s += v; ss += v * v;
  }
  __shared__ float rs[256], rq[256];
  rs[t] = s; rq[t] = ss; __syncthreads();
  for (int k = 128; k >= 1; k >>= 1){
    if (t < k){ rs[t] += rs[t + k]; rq[t] += rq[t + k]; }
    __syncthreads();
  }
  if (t == 0){
    float m = rs[0] * (1.f / 8192.f), e2 = rq[0] * (1.f / 8192.f);
    float var = e2 - m * m; if (var < 0.f) var = 0.f;
    float scv = g[o] * rsqrtf(var + BN_EPS);
    sc[o] = scv; sh[o] = b[o] - m * scv;
  }
}

__global__ void kapply(const u16* __restrict__ finpre, const float* __restrict__ sc,
                       const float* __restrict__ sh, float* __restrict__ out){
  int i = blockIdx.x * 256 + threadIdx.x;
  if (i >= 32 * 512 * 256) return;
  int o = (i >> 8) & 511;
  float v = sc[o] * bf2f(finpre[i]) + sh[o];
  out[i] = v > 0.f ? v : 0.2f * v;
}

// ================================================================ host
extern "C" void kernel_launch(void* const* d_in, const int* in_sizes, int n_in,
                              void* d_out, int out_size, void* d_ws, size_t ws_size,
                              hipStream_t stream){
  const float* x    = (const float*)d_in[0];
  const float* w_c1 = (const float*)d_in[1];
  const float* g1   = (const float*)d_in[2];
  const float* b1   = (const float*)d_in[3];
  const float* w_c2 = (const float*)d_in[4];
  const float* g2   = (const float*)d_in[5];
  const float* b2   = (const float*)d_in[6];
  const float* l0w1 = (const float*)d_in[7];
  const float* l0g1 = (const float*)d_in[8];
  const float* l0b1 = (const float*)d_in[9];
  const float* l0w2 = (const float*)d_in[10];
  const float* l0g2 = (const float*)d_in[11];
  const float* l0b2 = (const float*)d_in[12];
  const float* l1w1 = (const float*)d_in[13];
  const float* l1g1 = (const float*)d_in[14];
  const float* l1b1 = (const float*)d_in[15];
  const float* l1w2 = (const float*)d_in[16];
  const float* l1g2 = (const float*)d_in[17];
  const float* l1b2 = (const float*)d_in[18];
  const float* wf   = (const float*)d_in[19];
  const float* gf   = (const float*)d_in[20];
  const float* bfp  = (const float*)d_in[21];
  float* out = (float*)d_out;

  char* ws = (char*)d_ws;
  size_t cur = 0;
  auto alloc = [&](size_t bytes) -> char* {
    char* p = ws + cur;
    cur += (bytes + 255) & ~(size_t)255;
    return p;
  };
  float* sc1  = (float*)alloc(64 * 4);    float* sh1  = (float*)alloc(64 * 4);
  float* scSK = (float*)alloc(1024 * 4);  float* shSK = (float*)alloc(1024 * 4);
  float* scA1 = (float*)alloc(128 * 4);   float* shA1 = (float*)alloc(128 * 4);
  float* scA2 = (float*)alloc(128 * 4);   float* shA2 = (float*)alloc(128 * 4);
  float* scC1 = (float*)alloc(256 * 4);   float* shC1 = (float*)alloc(256 * 4);
  float* scC2 = (float*)alloc(256 * 4);   float* shC2 = (float*)alloc(256 * 4);
  float* scF  = (float*)alloc(512 * 4);   float* shF  = (float*)alloc(512 * 4);
  u16* w1bf1 = (u16*)alloc((size_t)128 * 64 * 2);
  u16* w2bf1 = (u16*)alloc((size_t)128 * 128 * 2);
  u16* w1bf2 = (u16*)alloc((size_t)256 * 128 * 2);
  u16* w2bf2 = (u16*)alloc((size_t)256 * 256 * 2);
  u16*   featT  = (u16*)  alloc((size_t)32 * 1024 * 64 * 2);
  u16*   xpre   = (u16*)  alloc((size_t)32 * 1024 * 256 * 2);
  int*   fidx1  = (int*)  alloc((size_t)32 * 512 * 4);
  float* nxyz1  = (float*)alloc((size_t)32 * 512 * 3 * 4);
  int*   knn1   = (int*)  alloc((size_t)32 * 512 * 32 * 4);
  int*   fidx2  = (int*)  alloc((size_t)32 * 256 * 4);
  float* nxyz2  = (float*)alloc((size_t)32 * 256 * 3 * 4);
  int*   knn2   = (int*)  alloc((size_t)32 * 256 * 32 * 4);
  u16*   pre1   = (u16*)  alloc((size_t)16384 * 128 * 32 * 2);  // == 8192*256*32, reused by stage 2
  float* part   = (float*)alloc((size_t)16384 * 128 * 2 * 4);   // == 8192*256*2, reused by stage 2
  float* pooledPre = (float*)alloc((size_t)16384 * 128 * 4);    // == 8192*256, reused by stage 2
  u16*   f0feat = (u16*)  alloc((size_t)16384 * 128 * 2);
  u16*   f1T    = (u16*)  alloc((size_t)32 * 256 * 256 * 2);
  u16*   finpre = (u16*)  alloc((size_t)32 * 512 * 256 * 2);

  if (cur > ws_size){
    float code = -1000.f - (float)(ws_size >> 20);
    kfb<<<(out_size + 255) / 256, 256, 0, stream>>>(out, out_size, code);
    return;
  }

  // bf16 weight casts (left half of w1; full w2)
  kcast_bf<<<(128 * 64 + 255) / 256, 256, 0, stream>>>(l0w1, 128, 64, 128, 0, w1bf1);
  kcast_bf<<<(128 * 128 + 255) / 256, 256, 0, stream>>>(l0w2, 128, 128, 128, 0, w2bf1);
  kcast_bf<<<(256 * 128 + 255) / 256, 256, 0, stream>>>(l1w1, 256, 128, 256, 0, w1bf2);
  kcast_bf<<<(256 * 256 + 255) / 256, 256, 0, stream>>>(l1w2, 256, 256, 256, 0, w2bf2);

  // stage A
  kA_stats<<<64, 256, 0, stream>>>(x, w_c1, g1, b1, sc1, sh1);
  kA_feat<<<128, 256, 0, stream>>>(x, w_c1, sc1, sh1, featT);

  // x_skip
  kxskip_pre<<<512, 256, 0, stream>>>(featT, w_c2, xpre);
  kxskip_stats<<<1024, 256, 0, stream>>>(xpre, g2, b2, scSK, shSK);

  // stage 1 selections (register-resident FPS)
  kfps<1024, 512, 1><<<32, 64, 0, stream>>>(x, x + 1024, x + 2048, 6144, fidx1, nxyz1);
  kknn<1024, 512><<<32 * 512 / 4, 256, 0, stream>>>(x, x + 1024, x + 2048, 6144, 1, nxyz1, knn1);

  // stage 1 local_op (pre -> stats -> post)
  kgm_pre<64, 128, 1024, 9><<<16384, 256, 0, stream>>>(featT, knn1, fidx1, l0w1, w1bf1, pre1, part);
  kstats_part<128, 16384><<<128, 256, 0, stream>>>(part, l0g1, l0b1, scA1, shA1);
  kgm_post<128><<<16384, 256, 0, stream>>>(pre1, scA1, shA1, w2bf1, l0g2, part, pooledPre);
  kstats_part<128, 16384><<<128, 256, 0, stream>>>(part, l0g2, l0b2, scA2, shA2);
  kpool_fin1<<<8192, 256, 0, stream>>>(pooledPre, scA2, shA2, f0feat);

  // stage 2 selections
  kfps<512, 256, 3><<<32, 64, 0, stream>>>(nxyz1, nxyz1 + 1, nxyz1 + 2, 1536, fidx2, nxyz2);
  kknn<512, 256><<<32 * 256 / 4, 256, 0, stream>>>(nxyz1, nxyz1 + 1, nxyz1 + 2, 1536, 3, nxyz2, knn2);

  // stage 2 local_op
  kgm_pre<128, 256, 512, 8><<<8192, 256, 0, stream>>>(f0feat, knn2, fidx2, l1w1, w1bf2, pre1, part);
  kstats_part<256, 8192><<<256, 256, 0, stream>>>(part, l1g1, l1b1, scC1, shC1);
  kgm_post<256><<<8192, 256, 0, stream>>>(pre1, scC1, shC1, w2bf2, l1g2, part, pooledPre);
  kstats_part<256, 8192><<<256, 256, 0, stream>>>(part, l1g2, l1b2, scC2, shC2);
  kpool_finT<<<8192, 256, 0, stream>>>(pooledPre, scC2, shC2, f1T);

  // final
  kfinal8<<<2048, 256, 0, stream>>>(f1T, xpre, scSK, shSK, wf, finpre);
  kstats_fin<<<512, 256, 0, stream>>>(finpre, gf, bfp, scF, shF);
  kapply<<<16384, 256, 0, stream>>>(finpre, scF, shF, out);
}